// Round 7
// baseline (384.210 us; speedup 1.0000x reference)
//
#include <hip/hip_runtime.h>
#include <cmath>

constexpr int B_ = 4, H_ = 8, TQ_ = 128, TK_ = 128, DH_ = 64;
constexpr int NMEM = 100000, DM = 512, TOPK = 32, HID = 128;
constexpr int R_ = B_ * TQ_;                    // 512 memory rows (b,t)
constexpr int CTILE = 128, RTILE = 64;
constexpr int NCHP = 784;                       // padded chunk count (8 XCDs x 98)
constexpr int NPAD = NCHP * CTILE;              // 100352 padded rows
constexpr int KC = 16;                          // candidates kept per chunk
constexpr int NCAND = NCHP * KC;                // 12544 = 49*256
constexpr int KSEL = 48;                        // min rescored candidates
constexpr int CAP  = 128;                       // max rescored candidates
constexpr int NLD  = NCAND / 256;               // 49 keys per thread (exact)

using f32x4  = __attribute__((ext_vector_type(4))) float;
using bf16x8 = __attribute__((ext_vector_type(8))) short;
using u16x8  = __attribute__((ext_vector_type(8))) unsigned short;

#define GLOAD16(g, l) __builtin_amdgcn_global_load_lds( \
    (const __attribute__((address_space(1))) void*)(g), \
    (__attribute__((address_space(3))) void*)(l), 16, 0, 0)

static __device__ __forceinline__ unsigned short f2bf(float f) {
    unsigned u = __float_as_uint(f);
    u = (u + 0x7FFFu + ((u >> 16) & 1u)) >> 16;
    return (unsigned short)u;
}

// ---------------------------------------------------------------- k0: fp32 -> bf16 (mk padded + qm, one kernel)
__global__ __launch_bounds__(256)
void k0_cvt(const float* __restrict__ mk, const float* __restrict__ qm,
            unsigned short* __restrict__ dst)
{
    const long totalmk = (long)NPAD * DM;          // bf16 elements for mk region
    const long nvalid  = (long)NMEM * DM;
    const long total   = totalmk + (long)R_ * DM;
    long stride = (long)gridDim.x * 256 * 8;
    for (long base = ((long)blockIdx.x * 256 + threadIdx.x) * 8; base < total; base += stride) {
        u16x8 o;
        const float* src = nullptr;
        long off = 0;
        if (base < totalmk) {
            if (base < nvalid) { src = mk; off = base; }
        } else { src = qm; off = base - totalmk; }
        if (src) {
            float4 v0 = *reinterpret_cast<const float4*>(src + off);
            float4 v1 = *reinterpret_cast<const float4*>(src + off + 4);
            o[0] = f2bf(v0.x); o[1] = f2bf(v0.y); o[2] = f2bf(v0.z); o[3] = f2bf(v0.w);
            o[4] = f2bf(v1.x); o[5] = f2bf(v1.y); o[6] = f2bf(v1.z); o[7] = f2bf(v1.w);
        } else {
            o = (u16x8)0;
        }
        *reinterpret_cast<u16x8*>(dst + base) = o;
    }
}

// ---------------------------------------------------------------- kW: Wcomb = W1k @ Wk  (128 x 512)
__global__ __launch_bounds__(256)
void kW_comb(const float* __restrict__ W1, const float* __restrict__ Wk,
             float* __restrict__ Wcomb)
{
    const int e = blockIdx.x;        // 0..127
    const int tid = threadIdx.x;
    __shared__ float w1s[DH_];
    if (tid < DH_) w1s[tid] = W1[(size_t)e * (2 * DH_) + DH_ + tid];
    __syncthreads();
    for (int dm = tid; dm < DM; dm += 256) {
        float acc = 0.f;
#pragma unroll 8
        for (int d = 0; d < DH_; ++d)
            acc = fmaf(w1s[d], Wk[(size_t)d * DM + dm], acc);
        Wcomb[(size_t)e * DM + dm] = acc;
    }
}

// ---------------------------------------------------------------- k1: bf16 MFMA scores + per-chunk top-16 (gload_lds)
__global__ __launch_bounds__(256)
void k1_mfma(const unsigned short* __restrict__ qmb, const unsigned short* __restrict__ mkb,
             unsigned* __restrict__ cand_k, int* __restrict__ cand_i)
{
    // XCD-aware decomposition: blocks sharing a chunk land consecutively on
    // the SAME XCD so the B tile is fetched into that XCD's L2 exactly once.
    const int wgid = blockIdx.x;          // 0..6271
    const int xcd = wgid & 7;
    const int k9 = wgid >> 3;             // 0..783
    const int chunk = xcd * 98 + (k9 >> 3);
    const int rt = k9 & 7;
    const int row0 = rt * RTILE;
    const int col0 = chunk * CTILE;
    const int tid = threadIdx.x;
    const int lane = tid & 63, w = tid >> 6;
    const int wm = w >> 1, wn = w & 1;    // wave computes 32x64

    // union: A[64][64]bf16 @0 (8 KiB) + B[128][64]bf16 @8192 (16 KiB)  |  sc[64][132] f32
    __shared__ __align__(16) char smem[64 * 132 * 4];
    char* Abase = smem;
    char* Bbase = smem + 8192;
    float* scf = (float*)smem;

    // hoisted staging source pointers (swizzled source, linear LDS dest)
    const char* srcA[2];
    const char* srcB[4];
#pragma unroll
    for (int p = 0; p < 2; ++p) {
        int X = p * 4096 + w * 1024 + lane * 16;
        int r = X >> 7, c = (X & 127) ^ ((r & 7) << 4);
        srcA[p] = (const char*)qmb + (size_t)(row0 + r) * 1024 + c;
    }
#pragma unroll
    for (int p = 0; p < 4; ++p) {
        int X = p * 4096 + w * 1024 + lane * 16;
        int r = X >> 7, c = (X & 127) ^ ((r & 7) << 4);
        srcB[p] = (const char*)mkb + (size_t)(col0 + r) * 1024 + c;
    }
    // hoisted LDS fragment byte-offsets
    int aoff[2][2], boff[4][2];
#pragma unroll
    for (int mi = 0; mi < 2; ++mi) {
        int rr = wm * 32 + mi * 16 + (lane & 15);
        int bse = rr * 128 + ((lane >> 4) * 16);
        aoff[mi][0] = bse ^ ((rr & 7) << 4);
        aoff[mi][1] = (bse + 64) ^ ((rr & 7) << 4);
    }
#pragma unroll
    for (int ni = 0; ni < 4; ++ni) {
        int rr = wn * 64 + ni * 16 + (lane & 15);
        int bse = rr * 128 + ((lane >> 4) * 16);
        boff[ni][0] = 8192 + (bse ^ ((rr & 7) << 4));
        boff[ni][1] = 8192 + ((bse + 64) ^ ((rr & 7) << 4));
    }

    f32x4 acc[2][4];
#pragma unroll
    for (int mi = 0; mi < 2; ++mi)
#pragma unroll
        for (int ni = 0; ni < 4; ++ni) acc[mi][ni] = (f32x4)0.f;

    for (int ks = 0; ks < 8; ++ks) {
#pragma unroll
        for (int p = 0; p < 2; ++p) {
            GLOAD16(srcA[p], Abase + p * 4096 + w * 1024);
            srcA[p] += 128;
        }
#pragma unroll
        for (int p = 0; p < 4; ++p) {
            GLOAD16(srcB[p], Bbase + p * 4096 + w * 1024);
            srcB[p] += 128;
        }
        __syncthreads();
#pragma unroll
        for (int kk = 0; kk < 2; ++kk) {
            bf16x8 af[2], bfr[4];
#pragma unroll
            for (int mi = 0; mi < 2; ++mi)
                af[mi] = *reinterpret_cast<const bf16x8*>(smem + aoff[mi][kk]);
#pragma unroll
            for (int ni = 0; ni < 4; ++ni)
                bfr[ni] = *reinterpret_cast<const bf16x8*>(smem + boff[ni][kk]);
#pragma unroll
            for (int mi = 0; mi < 2; ++mi)
#pragma unroll
                for (int ni = 0; ni < 4; ++ni)
                    acc[mi][ni] = __builtin_amdgcn_mfma_f32_16x16x32_bf16(af[mi], bfr[ni], acc[mi][ni], 0, 0, 0);
        }
        __syncthreads();
    }

    // scores -> LDS (C/D layout: col=lane&15, row=(lane>>4)*4+reg), OOB cols masked; stride 132
#pragma unroll
    for (int mi = 0; mi < 2; ++mi)
#pragma unroll
        for (int ni = 0; ni < 4; ++ni)
#pragma unroll
            for (int reg = 0; reg < 4; ++reg) {
                int rr = wm * 32 + mi * 16 + (lane >> 4) * 4 + reg;
                int cc = wn * 64 + ni * 16 + (lane & 15);
                scf[rr * 132 + cc] = (col0 + cc < NMEM) ? acc[mi][ni][reg] : -INFINITY;
            }
    __syncthreads();

    // single-pass per-thread top-4 over a strided 32-element slice (4 threads per row)
    const int rid = tid >> 2, sub = tid & 3;
    const float* srow = scf + rid * 132;
    unsigned long long t0 = 0ull, t1 = 0ull, t2 = 0ull, t3 = 0ull;
#pragma unroll 8
    for (int i = 0; i < 32; ++i) {
        int c = sub + 4 * i;
        float v = srow[c];
        unsigned b = __float_as_uint(v);
        unsigned s = b ^ ((unsigned)((int)b >> 31) | 0x80000000u);   // order-preserving key
        unsigned long long k = ((unsigned long long)s << 7) | (unsigned)(127 - c);
        bool g0 = k > t0, g1 = k > t1, g2 = k > t2, g3 = k > t3;
        unsigned long long n0 = g0 ? k : t0;
        unsigned long long n1 = g0 ? t0 : (g1 ? k : t1);
        unsigned long long n2 = g1 ? t1 : (g2 ? k : t2);
        unsigned long long n3 = g2 ? t2 : (g3 ? k : t3);
        t0 = n0; t1 = n1; t2 = n2; t3 = n3;
    }
    size_t base = (size_t)(row0 + rid) * NCAND + (size_t)chunk * KC + sub * 4;
    uint4 kv, iv;
    kv.x = (unsigned)(t0 >> 7); iv.x = col0 + 127 - (int)(t0 & 127u);
    kv.y = (unsigned)(t1 >> 7); iv.y = col0 + 127 - (int)(t1 & 127u);
    kv.z = (unsigned)(t2 >> 7); iv.z = col0 + 127 - (int)(t2 & 127u);
    kv.w = (unsigned)(t3 >> 7); iv.w = col0 + 127 - (int)(t3 & 127u);
    *reinterpret_cast<uint4*>(cand_k + base) = kv;
    *reinterpret_cast<uint4*>(cand_i + base) = iv;
}

// ---------------------------------------------------------------- k2a: threshold select (radix binary search) + gather
__global__ __launch_bounds__(256)
void k2a_thresh(const unsigned* __restrict__ cand_k, const int* __restrict__ cand_i,
                int* __restrict__ cand2_i, int* __restrict__ cand2_n)
{
    const int row = blockIdx.x;
    const int tid = threadIdx.x;
    const int lane = tid & 63, wv = tid >> 6;
    const unsigned* ck = cand_k + (size_t)row * NCAND;

    unsigned key[NLD];
#pragma unroll
    for (int j = 0; j < NLD; ++j) key[j] = ck[tid + j * 256];

    __shared__ int red[4];
    __shared__ int cnt;
    unsigned lo = 0u;
    int c_cur = NCAND;
    for (int bit = 31; bit >= 0; --bit) {
        if (c_cur <= CAP) break;   // uniform across block
        unsigned T = lo | (1u << bit);
        int c = 0;
#pragma unroll
        for (int j = 0; j < NLD; ++j) c += (key[j] >= T);
#pragma unroll
        for (int off = 1; off < 64; off <<= 1) c += __shfl_xor(c, off);
        if (lane == 0) red[wv] = c;
        __syncthreads();
        int ct = red[0] + red[1] + red[2] + red[3];
        if (ct >= KSEL) { lo = T; c_cur = ct; }
        __syncthreads();
    }

    if (tid == 0) cnt = 0;
    __syncthreads();
#pragma unroll
    for (int j = 0; j < NLD; ++j) {
        if (key[j] >= lo) {
            int p = atomicAdd(&cnt, 1);
            if (p < CAP) cand2_i[(size_t)row * CAP + p] = cand_i[(size_t)row * NCAND + tid + j * 256];
        }
    }
    __syncthreads();
    if (tid == 0) cand2_n[row] = cnt < CAP ? cnt : CAP;
}

// ---------------------------------------------------------------- k2b: fp64 rescore (one wave per candidate, float4 loads)
__global__ __launch_bounds__(256)
void k2b_rescore(const float* __restrict__ qm, const float* __restrict__ mk,
                 const int* __restrict__ cand2_i, const int* __restrict__ cand2_n,
                 double* __restrict__ rsc)
{
    const int row = blockIdx.x;
    const int tid = threadIdx.x;
    const int lane = tid & 63, wv = tid >> 6;
    const int c = blockIdx.y * 4 + wv;
    const int n = cand2_n[row];
    if (c >= n) return;
    const int idx = cand2_i[(size_t)row * CAP + c];
    const float4* q4 = reinterpret_cast<const float4*>(qm + (size_t)row * DM);
    const float4* k4 = reinterpret_cast<const float4*>(mk + (size_t)idx * DM);
    float4 a0 = q4[lane], b0 = k4[lane];
    float4 a1 = q4[lane + 64], b1 = k4[lane + 64];
    double p = (double)a0.x * b0.x + (double)a0.y * b0.y
             + (double)a0.z * b0.z + (double)a0.w * b0.w
             + (double)a1.x * b1.x + (double)a1.y * b1.y
             + (double)a1.z * b1.z + (double)a1.w * b1.w;
#pragma unroll
    for (int off = 1; off < 64; off <<= 1) p += __shfl_xor(p, off);
    if (lane == 0) rsc[(size_t)row * CAP + c] = p;
}

// ---------------------------------------------------------------- k2c: exact ordered top-32 (one wave per row)
__global__ __launch_bounds__(64)
void k2c_top32(const double* __restrict__ rsc, const int* __restrict__ cand2_i,
               const int* __restrict__ cand2_n, int* __restrict__ sel)
{
    const int row = blockIdx.x;
    const int lane = threadIdx.x;
    const int n = cand2_n[row];
    double v0 = -1.0e300, v1 = -1.0e300;
    int i0 = 0x7fffffff, i1 = 0x7fffffff;
    if (lane < n)      { v0 = rsc[(size_t)row * CAP + lane];      i0 = cand2_i[(size_t)row * CAP + lane]; }
    if (lane + 64 < n) { v1 = rsc[(size_t)row * CAP + lane + 64]; i1 = cand2_i[(size_t)row * CAP + lane + 64]; }
    for (int s = 0; s < TOPK; ++s) {
        double bv; int bi;
        if (v0 > v1 || (v0 == v1 && i0 < i1)) { bv = v0; bi = i0; }
        else                                  { bv = v1; bi = i1; }
#pragma unroll
        for (int off = 1; off < 64; off <<= 1) {
            double ov = __shfl_xor(bv, off);
            int    oi = __shfl_xor(bi, off);
            if (ov > bv || (ov == bv && oi < bi)) { bv = ov; bi = oi; }
        }
        if (lane == 0) sel[row * TOPK + s] = bi;
        if (i0 == bi) v0 = -1.0e300;
        if (i1 == bi) v1 = -1.0e300;
    }
}

// ---------------------------------------------------------------- k3: gather + {kmp via Wcomb, Vmem via Wv}
__global__ __launch_bounds__(192)
void k3_pv(const float* __restrict__ mk, const float* __restrict__ mv,
           const float* __restrict__ Wv, const float* __restrict__ Wcomb,
           const int* __restrict__ sel,
           float* __restrict__ kmp, float* __restrict__ Vmem)
{
    const int i0 = blockIdx.x * 16;   // pair base, pair = row*TOPK+k (16384 total)
    const int tid = threadIdx.x;      // 192
    __shared__ float sK[16][DM];      // 32 KiB
    __shared__ float sV[16][DM];      // 32 KiB
    __shared__ int si[16];
    if (tid < 16) si[tid] = sel[i0 + tid];
    __syncthreads();
    for (int l = tid; l < 4096; l += 192) {   // 2 mats x 16 rows x 128 float4
        int mat = l >> 11, r = (l >> 7) & 15, c4 = l & 127;
        const float* src = (mat ? mv : mk) + (size_t)si[r] * DM + c4 * 4;
        float4 v = *reinterpret_cast<const float4*>(src);
        float* dstp = (mat ? &sV[r][c4 * 4] : &sK[r][c4 * 4]);
        *reinterpret_cast<float4*>(dstp) = v;
    }
    __syncthreads();

    if (tid < HID) {
        // kmp output e = tid over 16 rows
        const float* wrow = Wcomb + (size_t)tid * DM;
        float acc[16];
#pragma unroll
        for (int r = 0; r < 16; ++r) acc[r] = 0.f;
        for (int d4 = 0; d4 < DM / 4; ++d4) {
            float4 wv4 = *reinterpret_cast<const float4*>(wrow + d4 * 4);
#pragma unroll
            for (int r = 0; r < 16; ++r) {
                float4 m = *reinterpret_cast<const float4*>(&sK[r][d4 * 4]);
                acc[r] = fmaf(wv4.x, m.x, fmaf(wv4.y, m.y, fmaf(wv4.z, m.z, fmaf(wv4.w, m.w, acc[r]))));
            }
        }
#pragma unroll
        for (int r = 0; r < 16; ++r)
            kmp[(size_t)(i0 + r) * HID + tid] = acc[r];
    } else {
        // Vmem output e = tid-128 over 16 rows
        const int e = tid - HID;      // 0..63
        const float* wrow = Wv + (size_t)e * DM;
        float acc[16];
#pragma unroll
        for (int r = 0; r < 16; ++r) acc[r] = 0.f;
        for (int d4 = 0; d4 < DM / 4; ++d4) {
            float4 wv4 = *reinterpret_cast<const float4*>(wrow + d4 * 4);
#pragma unroll
            for (int r = 0; r < 16; ++r) {
                float4 m = *reinterpret_cast<const float4*>(&sV[r][d4 * 4]);
                acc[r] = fmaf(wv4.x, m.x, fmaf(wv4.y, m.y, fmaf(wv4.z, m.z, fmaf(wv4.w, m.w, acc[r]))));
            }
        }
#pragma unroll
        for (int r = 0; r < 16; ++r)
            Vmem[(size_t)(i0 + r) * DH_ + e] = acc[r];
    }
}

// ---------------------------------------------------------------- k4: W1 partial projections (q, kctx only)
__global__ __launch_bounds__(128)
void k4_parts(const float* __restrict__ q, const float* __restrict__ kctx,
              const float* __restrict__ W1,
              float* __restrict__ qp, float* __restrict__ kcp)
{
    const int bid = blockIdx.x;
    const int tid = threadIdx.x;  // 128 = e
    const float* src; float* dst; int woff;
    if (bid < 1024)      { int r0 = bid * 4;          src = q    + (size_t)r0 * DH_; dst = qp  + (size_t)r0 * HID; woff = 0; }
    else                 { int r0 = (bid - 1024) * 4; src = kctx + (size_t)r0 * DH_; dst = kcp + (size_t)r0 * HID; woff = DH_; }
    __shared__ float s[4][DH_];
    for (int l = tid; l < 4 * DH_; l += 128) s[l >> 6][l & 63] = src[l];
    __syncthreads();
    const float* wr = W1 + (size_t)tid * (2 * DH_) + woff;
    float a0 = 0.f, a1 = 0.f, a2 = 0.f, a3 = 0.f;
#pragma unroll 8
    for (int d = 0; d < DH_; ++d) {
        float w = wr[d];
        a0 = fmaf(s[0][d], w, a0);
        a1 = fmaf(s[1][d], w, a1);
        a2 = fmaf(s[2][d], w, a2);
        a3 = fmaf(s[3][d], w, a3);
    }
    dst[0 * HID + tid] = a0;
    dst[1 * HID + tid] = a1;
    dst[2 * HID + tid] = a2;
    dst[3 * HID + tid] = a3;
}

// ---------------------------------------------------------------- k5: MLP scores + softmax + weighted sum
__global__ __launch_bounds__(256)
void k5_attn(const float* __restrict__ qp, const float* __restrict__ kcp,
             const float* __restrict__ kmp, const float* __restrict__ vctx,
             const float* __restrict__ Vmem, const float* __restrict__ b1,
             const float* __restrict__ w2, const float* __restrict__ b2,
             float* __restrict__ out, float* __restrict__ outw)
{
    const int bid = blockIdx.x;
    const int t = bid & 127, h = (bid >> 7) & 7, b = bid >> 10;
    const int tid = threadIdx.x;
    const int lane = tid & 63, wv = tid >> 6;
    const int bh = b * H_ + h, bht = bh * TQ_ + t, bt = b * TQ_ + t;
    constexpr int NS = TK_ + TOPK;  // 160
    __shared__ float qps[HID], b1s[HID], w2s[HID];
    __shared__ float sc[NS];
    __shared__ float red[8];
    if (tid < HID) {
        qps[tid] = qp[(size_t)bht * HID + tid];
        b1s[tid] = b1[tid];
        w2s[tid] = w2[tid];
    }
    __syncthreads();
    const float bias2 = b2[0];
    if (tid < NS) {
        const float* kr = (tid < TK_) ? (kcp + ((size_t)bh * TK_ + tid) * HID)
                                      : (kmp + ((size_t)bt * TOPK + (tid - TK_)) * HID);
        float acc = 0.f;
#pragma unroll 4
        for (int e4 = 0; e4 < HID / 4; ++e4) {
            float4 kv = *reinterpret_cast<const float4*>(kr + e4 * 4);
            acc += fmaxf(qps[e4 * 4 + 0] + kv.x + b1s[e4 * 4 + 0], 0.f) * w2s[e4 * 4 + 0];
            acc += fmaxf(qps[e4 * 4 + 1] + kv.y + b1s[e4 * 4 + 1], 0.f) * w2s[e4 * 4 + 1];
            acc += fmaxf(qps[e4 * 4 + 2] + kv.z + b1s[e4 * 4 + 2], 0.f) * w2s[e4 * 4 + 2];
            acc += fmaxf(qps[e4 * 4 + 3] + kv.w + b1s[e4 * 4 + 3], 0.f) * w2s[e4 * 4 + 3];
        }
        sc[tid] = acc + bias2;
    }
    __syncthreads();
    float v = (tid < NS) ? sc[tid] : -INFINITY;
    float m = v;
#pragma unroll
    for (int off = 1; off < 64; off <<= 1) m = fmaxf(m, __shfl_xor(m, off));
    if (lane == 0) red[wv] = m;
    __syncthreads();
    if (tid == 0) red[4] = fmaxf(fmaxf(red[0], red[1]), fmaxf(red[2], red[3]));
    __syncthreads();
    const float mm = red[4];
    float e = (tid < NS) ? expf(v - mm) : 0.f;
    float ssum = e;
#pragma unroll
    for (int off = 1; off < 64; off <<= 1) ssum += __shfl_xor(ssum, off);
    if (lane == 0) red[wv] = ssum;
    __syncthreads();
    if (tid == 0) red[5] = red[0] + red[1] + red[2] + red[3];
    __syncthreads();
    const float inv = 1.f / red[5];
    if (tid < NS) {
        float w = e * inv;
        sc[tid] = w;
        outw[(size_t)bht * NS + tid] = w;
    }
    __syncthreads();
    if (tid < DH_) {
        float acc = 0.f;
        const float* vb = vctx + (size_t)bh * TK_ * DH_ + tid;
        for (int s2 = 0; s2 < TK_; ++s2) acc = fmaf(sc[s2], vb[(size_t)s2 * DH_], acc);
        const float* vm = Vmem + (size_t)bt * TOPK * DH_ + tid;
#pragma unroll
        for (int kk = 0; kk < TOPK; ++kk) acc = fmaf(sc[TK_ + kk], vm[(size_t)kk * DH_], acc);
        out[(size_t)bht * DH_ + tid] = acc;
    }
}

// ---------------------------------------------------------------- launch
extern "C" void kernel_launch(void* const* d_in, const int* in_sizes, int n_in,
                              void* d_out, int out_size, void* d_ws, size_t ws_size,
                              hipStream_t stream)
{
    const float* q    = (const float*)d_in[0];
    const float* kctx = (const float*)d_in[1];
    const float* vctx = (const float*)d_in[2];
    const float* qm   = (const float*)d_in[3];
    const float* mk   = (const float*)d_in[4];
    const float* mv   = (const float*)d_in[5];
    const float* Wk   = (const float*)d_in[6];
    const float* Wv   = (const float*)d_in[7];
    const float* W1   = (const float*)d_in[8];
    const float* b1   = (const float*)d_in[9];
    const float* w2   = (const float*)d_in[10];
    const float* b2   = (const float*)d_in[11];
    float* out  = (float*)d_out;
    float* outw = out + (size_t)B_ * H_ * TQ_ * DH_;

    char* w = (char*)d_ws;
    unsigned short* mkb = (unsigned short*)w; w += sizeof(unsigned short) * (size_t)NPAD * DM;
    unsigned short* qmb = (unsigned short*)w; w += sizeof(unsigned short) * R_ * DM;
    float* Wcomb  = (float*)w; w += sizeof(float) * HID * DM;
    unsigned* cand_k = (unsigned*)w; w += sizeof(unsigned) * (size_t)R_ * NCAND;
    int*   cand_i = (int*)w;   w += sizeof(int) * (size_t)R_ * NCAND;
    int*   cand2_i= (int*)w;   w += sizeof(int) * R_ * CAP;
    int*   cand2_n= (int*)w;   w += sizeof(int) * R_;
    double* rsc   = (double*)w; w += sizeof(double) * R_ * CAP;
    int*   sel    = (int*)w;   w += sizeof(int) * R_ * TOPK;
    float* Vmem   = (float*)w; w += sizeof(float) * R_ * TOPK * DH_;
    float* qp     = (float*)w; w += sizeof(float) * B_ * H_ * TQ_ * HID;
    float* kcp    = (float*)w; w += sizeof(float) * B_ * H_ * TK_ * HID;
    float* kmp    = (float*)w; w += sizeof(float) * R_ * TOPK * HID;

    hipLaunchKernelGGL(k0_cvt, dim3(4096), dim3(256), 0, stream, mk, qm, mkb);
    hipLaunchKernelGGL(kW_comb, dim3(HID), dim3(256), 0, stream, W1, Wk, Wcomb);
    hipLaunchKernelGGL(k1_mfma, dim3(NCHP * 8), dim3(256), 0, stream, qmb, mkb, cand_k, cand_i);
    hipLaunchKernelGGL(k2a_thresh, dim3(R_), dim3(256), 0, stream, cand_k, cand_i, cand2_i, cand2_n);
    hipLaunchKernelGGL(k2b_rescore, dim3(R_, CAP / 4), dim3(256), 0, stream, qm, mk, cand2_i, cand2_n, rsc);
    hipLaunchKernelGGL(k2c_top32, dim3(R_), dim3(64), 0, stream, rsc, cand2_i, cand2_n, sel);
    hipLaunchKernelGGL(k3_pv, dim3(R_ * TOPK / 16), dim3(192), 0, stream, mk, mv, Wv, Wcomb, sel, kmp, Vmem);
    hipLaunchKernelGGL(k4_parts, dim3(2048), dim3(128), 0, stream, q, kctx, W1, qp, kcp);
    hipLaunchKernelGGL(k5_attn, dim3(B_ * H_ * TQ_), dim3(256), 0, stream, qp, kcp, kmp, vctx, Vmem, b1, w2, b2, out, outw);
}

// Round 8
// 379.883 us; speedup vs baseline: 1.0114x; 1.0114x over previous
//
#include <hip/hip_runtime.h>
#include <cmath>

constexpr int B_ = 4, H_ = 8, TQ_ = 128, TK_ = 128, DH_ = 64;
constexpr int NMEM = 100000, DM = 512, TOPK = 32, HID = 128;
constexpr int R_ = B_ * TQ_;                    // 512 memory rows (b,t)
constexpr int CTILE = 128, RTILE = 128;         // 128x128 output tile (m97 geometry)
constexpr int NCHP = 784;                       // padded chunk count (8 XCDs x 98)
constexpr int NPAD = NCHP * CTILE;              // 100352 padded rows
constexpr int KC = 16;                          // candidates kept per chunk
constexpr int NCAND = NCHP * KC;                // 12544 = 49*256
constexpr int KSEL = 48;                        // min rescored candidates
constexpr int CAP  = 128;                       // max rescored candidates
constexpr int NLD  = NCAND / 256;               // 49 keys per thread (exact)

using f32x4  = __attribute__((ext_vector_type(4))) float;
using bf16x8 = __attribute__((ext_vector_type(8))) short;
using u16x8  = __attribute__((ext_vector_type(8))) unsigned short;

#define GLOAD16(g, l) __builtin_amdgcn_global_load_lds( \
    (const __attribute__((address_space(1))) void*)(g), \
    (__attribute__((address_space(3))) void*)(l), 16, 0, 0)

static __device__ __forceinline__ unsigned short f2bf(float f) {
    unsigned u = __float_as_uint(f);
    u = (u + 0x7FFFu + ((u >> 16) & 1u)) >> 16;
    return (unsigned short)u;
}

// ---------------------------------------------------------------- k0: fp32 -> bf16 (mk padded + qm, one kernel)
__global__ __launch_bounds__(256)
void k0_cvt(const float* __restrict__ mk, const float* __restrict__ qm,
            unsigned short* __restrict__ dst)
{
    const long totalmk = (long)NPAD * DM;          // bf16 elements for mk region
    const long nvalid  = (long)NMEM * DM;
    const long total   = totalmk + (long)R_ * DM;
    long stride = (long)gridDim.x * 256 * 8;
    for (long base = ((long)blockIdx.x * 256 + threadIdx.x) * 8; base < total; base += stride) {
        u16x8 o;
        const float* src = nullptr;
        long off = 0;
        if (base < totalmk) {
            if (base < nvalid) { src = mk; off = base; }
        } else { src = qm; off = base - totalmk; }
        if (src) {
            float4 v0 = *reinterpret_cast<const float4*>(src + off);
            float4 v1 = *reinterpret_cast<const float4*>(src + off + 4);
            o[0] = f2bf(v0.x); o[1] = f2bf(v0.y); o[2] = f2bf(v0.z); o[3] = f2bf(v0.w);
            o[4] = f2bf(v1.x); o[5] = f2bf(v1.y); o[6] = f2bf(v1.z); o[7] = f2bf(v1.w);
        } else {
            o = (u16x8)0;
        }
        *reinterpret_cast<u16x8*>(dst + base) = o;
    }
}

// ---------------------------------------------------------------- k1: bf16 MFMA 128x128 tile + per-chunk top-16
__global__ __launch_bounds__(256)
void k1_mfma(const unsigned short* __restrict__ qmb, const unsigned short* __restrict__ mkb,
             unsigned* __restrict__ cand_k, int* __restrict__ cand_i)
{
    // XCD-aware decomposition: the 4 blocks sharing a chunk land consecutively
    // on the SAME XCD so the B tile is fetched into that XCD's L2 exactly once.
    const int wgid = blockIdx.x;          // 0..3135
    const int xcd = wgid & 7;
    const int k9 = wgid >> 3;             // 0..391
    const int chunk = xcd * 98 + (k9 >> 2);
    const int rt = k9 & 3;
    const int row0 = rt * RTILE;
    const int col0 = chunk * CTILE;
    const int tid = threadIdx.x;
    const int lane = tid & 63, w = tid >> 6;
    const int wm = w >> 1, wn = w & 1;    // wave computes 64x64

    // LDS: A[128][64]bf16 @0 (16 KiB) + B[128][64]bf16 @16384 (16 KiB)
    //      union with selection scratch sc[64][132] f32 (33792 B)
    __shared__ __align__(16) char smem[64 * 132 * 4];
    char* Abase = smem;
    char* Bbase = smem + 16384;
    float* scf = (float*)smem;

    // hoisted staging source pointers (swizzled source, linear LDS dest)
    const char* srcA[4];
    const char* srcB[4];
#pragma unroll
    for (int p = 0; p < 4; ++p) {
        int X = p * 4096 + w * 1024 + lane * 16;
        int r = X >> 7, c = (X & 127) ^ ((r & 7) << 4);
        srcA[p] = (const char*)qmb + (size_t)(row0 + r) * 1024 + c;
        srcB[p] = (const char*)mkb + (size_t)(col0 + r) * 1024 + c;
    }
    // hoisted LDS fragment byte-offsets
    int aoff[4][2], boff[4][2];
#pragma unroll
    for (int mi = 0; mi < 4; ++mi) {
        int rr = wm * 64 + mi * 16 + (lane & 15);
        int bse = rr * 128 + ((lane >> 4) * 16);
        aoff[mi][0] = bse ^ ((rr & 7) << 4);
        aoff[mi][1] = (bse + 64) ^ ((rr & 7) << 4);
    }
#pragma unroll
    for (int ni = 0; ni < 4; ++ni) {
        int rr = wn * 64 + ni * 16 + (lane & 15);
        int bse = rr * 128 + ((lane >> 4) * 16);
        boff[ni][0] = 16384 + (bse ^ ((rr & 7) << 4));
        boff[ni][1] = 16384 + ((bse + 64) ^ ((rr & 7) << 4));
    }

    f32x4 acc[4][4];
#pragma unroll
    for (int mi = 0; mi < 4; ++mi)
#pragma unroll
        for (int ni = 0; ni < 4; ++ni) acc[mi][ni] = (f32x4)0.f;

    for (int ks = 0; ks < 8; ++ks) {
#pragma unroll
        for (int p = 0; p < 4; ++p) {
            GLOAD16(srcA[p], Abase + p * 4096 + w * 1024);
            srcA[p] += 128;
            GLOAD16(srcB[p], Bbase + p * 4096 + w * 1024);
            srcB[p] += 128;
        }
        __syncthreads();
#pragma unroll
        for (int kk = 0; kk < 2; ++kk) {
            bf16x8 af[4], bfr[4];
#pragma unroll
            for (int mi = 0; mi < 4; ++mi)
                af[mi] = *reinterpret_cast<const bf16x8*>(smem + aoff[mi][kk]);
#pragma unroll
            for (int ni = 0; ni < 4; ++ni)
                bfr[ni] = *reinterpret_cast<const bf16x8*>(smem + boff[ni][kk]);
#pragma unroll
            for (int mi = 0; mi < 4; ++mi)
#pragma unroll
                for (int ni = 0; ni < 4; ++ni)
                    acc[mi][ni] = __builtin_amdgcn_mfma_f32_16x16x32_bf16(af[mi], bfr[ni], acc[mi][ni], 0, 0, 0);
        }
        __syncthreads();
    }

    // selection in two row-halves (sc[64][132] unions with staging LDS)
    const int rid = tid >> 2, sub = tid & 3;
#pragma unroll
    for (int h = 0; h < 2; ++h) {
        if (wm == h) {
            // scores -> LDS (C/D layout: col=lane&15, row=(lane>>4)*4+reg); stride 132
#pragma unroll
            for (int mi = 0; mi < 4; ++mi)
#pragma unroll
                for (int ni = 0; ni < 4; ++ni)
#pragma unroll
                    for (int reg = 0; reg < 4; ++reg) {
                        int rr = mi * 16 + (lane >> 4) * 4 + reg;      // 0..63 local
                        int cc = wn * 64 + ni * 16 + (lane & 15);
                        scf[rr * 132 + cc] = (col0 + cc < NMEM) ? acc[mi][ni][reg] : -INFINITY;
                    }
        }
        __syncthreads();

        // single-pass per-thread top-4 over a strided 32-element slice (4 threads/row)
        const float* srow = scf + rid * 132;
        unsigned long long t0 = 0ull, t1 = 0ull, t2 = 0ull, t3 = 0ull;
#pragma unroll 8
        for (int i = 0; i < 32; ++i) {
            int c = sub + 4 * i;
            float v = srow[c];
            unsigned b = __float_as_uint(v);
            unsigned s = b ^ ((unsigned)((int)b >> 31) | 0x80000000u);   // order-preserving key
            unsigned long long k = ((unsigned long long)s << 7) | (unsigned)(127 - c);
            bool g0 = k > t0, g1 = k > t1, g2 = k > t2, g3 = k > t3;
            unsigned long long n0 = g0 ? k : t0;
            unsigned long long n1 = g0 ? t0 : (g1 ? k : t1);
            unsigned long long n2 = g1 ? t1 : (g2 ? k : t2);
            unsigned long long n3 = g2 ? t2 : (g3 ? k : t3);
            t0 = n0; t1 = n1; t2 = n2; t3 = n3;
        }
        size_t base = (size_t)(row0 + h * 64 + rid) * NCAND + (size_t)chunk * KC + sub * 4;
        uint4 kv, iv;
        kv.x = (unsigned)(t0 >> 7); iv.x = col0 + 127 - (int)(t0 & 127u);
        kv.y = (unsigned)(t1 >> 7); iv.y = col0 + 127 - (int)(t1 & 127u);
        kv.z = (unsigned)(t2 >> 7); iv.z = col0 + 127 - (int)(t2 & 127u);
        kv.w = (unsigned)(t3 >> 7); iv.w = col0 + 127 - (int)(t3 & 127u);
        *reinterpret_cast<uint4*>(cand_k + base) = kv;
        *reinterpret_cast<uint4*>(cand_i + base) = iv;
        __syncthreads();
    }
}

// ---------------------------------------------------------------- k2a: threshold select (radix binary search) + gather
__global__ __launch_bounds__(256)
void k2a_thresh(const unsigned* __restrict__ cand_k, const int* __restrict__ cand_i,
                int* __restrict__ cand2_i, int* __restrict__ cand2_n)
{
    const int row = blockIdx.x;
    const int tid = threadIdx.x;
    const int lane = tid & 63, wv = tid >> 6;
    const unsigned* ck = cand_k + (size_t)row * NCAND;

    unsigned key[NLD];
#pragma unroll
    for (int j = 0; j < NLD; ++j) key[j] = ck[tid + j * 256];

    __shared__ int red[4];
    __shared__ int cnt;
    unsigned lo = 0u;
    int c_cur = NCAND;
    for (int bit = 31; bit >= 0; --bit) {
        if (c_cur <= CAP) break;   // uniform across block
        unsigned T = lo | (1u << bit);
        int c = 0;
#pragma unroll
        for (int j = 0; j < NLD; ++j) c += (key[j] >= T);
#pragma unroll
        for (int off = 1; off < 64; off <<= 1) c += __shfl_xor(c, off);
        if (lane == 0) red[wv] = c;
        __syncthreads();
        int ct = red[0] + red[1] + red[2] + red[3];
        if (ct >= KSEL) { lo = T; c_cur = ct; }
        __syncthreads();
    }

    if (tid == 0) cnt = 0;
    __syncthreads();
#pragma unroll
    for (int j = 0; j < NLD; ++j) {
        if (key[j] >= lo) {
            int p = atomicAdd(&cnt, 1);
            if (p < CAP) cand2_i[(size_t)row * CAP + p] = cand_i[(size_t)row * NCAND + tid + j * 256];
        }
    }
    __syncthreads();
    if (tid == 0) cand2_n[row] = cnt < CAP ? cnt : CAP;
}

// ---------------------------------------------------------------- k2b: fp64 rescore (one wave per candidate, float4 loads)
__global__ __launch_bounds__(256)
void k2b_rescore(const float* __restrict__ qm, const float* __restrict__ mk,
                 const int* __restrict__ cand2_i, const int* __restrict__ cand2_n,
                 double* __restrict__ rsc)
{
    const int row = blockIdx.x;
    const int tid = threadIdx.x;
    const int lane = tid & 63, wv = tid >> 6;
    const int c = blockIdx.y * 4 + wv;
    const int n = cand2_n[row];
    if (c >= n) return;
    const int idx = cand2_i[(size_t)row * CAP + c];
    const float4* q4 = reinterpret_cast<const float4*>(qm + (size_t)row * DM);
    const float4* k4 = reinterpret_cast<const float4*>(mk + (size_t)idx * DM);
    float4 a0 = q4[lane], b0 = k4[lane];
    float4 a1 = q4[lane + 64], b1 = k4[lane + 64];
    double p = (double)a0.x * b0.x + (double)a0.y * b0.y
             + (double)a0.z * b0.z + (double)a0.w * b0.w
             + (double)a1.x * b1.x + (double)a1.y * b1.y
             + (double)a1.z * b1.z + (double)a1.w * b1.w;
#pragma unroll
    for (int off = 1; off < 64; off <<= 1) p += __shfl_xor(p, off);
    if (lane == 0) rsc[(size_t)row * CAP + c] = p;
}

// ---------------------------------------------------------------- k2c: exact ordered top-32 (one wave per row)
__global__ __launch_bounds__(64)
void k2c_top32(const double* __restrict__ rsc, const int* __restrict__ cand2_i,
               const int* __restrict__ cand2_n, int* __restrict__ sel)
{
    const int row = blockIdx.x;
    const int lane = threadIdx.x;
    const int n = cand2_n[row];
    double v0 = -1.0e300, v1 = -1.0e300;
    int i0 = 0x7fffffff, i1 = 0x7fffffff;
    if (lane < n)      { v0 = rsc[(size_t)row * CAP + lane];      i0 = cand2_i[(size_t)row * CAP + lane]; }
    if (lane + 64 < n) { v1 = rsc[(size_t)row * CAP + lane + 64]; i1 = cand2_i[(size_t)row * CAP + lane + 64]; }
    for (int s = 0; s < TOPK; ++s) {
        double bv; int bi;
        if (v0 > v1 || (v0 == v1 && i0 < i1)) { bv = v0; bi = i0; }
        else                                  { bv = v1; bi = i1; }
#pragma unroll
        for (int off = 1; off < 64; off <<= 1) {
            double ov = __shfl_xor(bv, off);
            int    oi = __shfl_xor(bi, off);
            if (ov > bv || (ov == bv && oi < bi)) { bv = ov; bi = oi; }
        }
        if (lane == 0) sel[row * TOPK + s] = bi;
        if (i0 == bi) v0 = -1.0e300;
        if (i1 == bi) v1 = -1.0e300;
    }
}

// ---------------------------------------------------------------- k3: gather + Wk/Wv projection (round-4 proven)
__global__ __launch_bounds__(64)
void k3_proj(const float* __restrict__ mk, const float* __restrict__ mv,
             const float* __restrict__ Wk, const float* __restrict__ Wv,
             const int* __restrict__ sel,
             float* __restrict__ Kmem, float* __restrict__ Vmem)
{
    const int i0 = blockIdx.x * 8;   // pair base, pair = row*TOPK+k (16384 total)
    const int tid = threadIdx.x;     // 64
    __shared__ float s[2][8][DM];    // [mat][row][d] 32 KiB
    __shared__ int si[8];
    if (tid < 8) si[tid] = sel[i0 + tid];
    __syncthreads();
    for (int l = tid; l < 1024; l += 64) {   // 8 rows x 128 float4 per matrix
        int r = l >> 7, c4 = l & 127;
        *reinterpret_cast<float4*>(&s[0][r][c4 * 4]) =
            *reinterpret_cast<const float4*>(mk + (size_t)si[r] * DM + c4 * 4);
        *reinterpret_cast<float4*>(&s[1][r][c4 * 4]) =
            *reinterpret_cast<const float4*>(mv + (size_t)si[r] * DM + c4 * 4);
    }
    __syncthreads();
    const int doV = tid >> 5;        // 0: K path, 1: V path
    const int ep = tid & 31;         // handles e=ep and e=ep+32
    const float* W = doV ? Wv : Wk;
    const float* w0 = W + (size_t)ep * DM;
    const float* w1 = W + (size_t)(ep + 32) * DM;
    float a0[8], a1[8];
#pragma unroll
    for (int r = 0; r < 8; ++r) { a0[r] = 0.f; a1[r] = 0.f; }
    for (int d4 = 0; d4 < DM / 4; ++d4) {
        float4 x0 = *reinterpret_cast<const float4*>(w0 + d4 * 4);
        float4 x1 = *reinterpret_cast<const float4*>(w1 + d4 * 4);
#pragma unroll
        for (int r = 0; r < 8; ++r) {
            float4 m = *reinterpret_cast<const float4*>(&s[doV][r][d4 * 4]);
            a0[r] = fmaf(x0.x, m.x, fmaf(x0.y, m.y, fmaf(x0.z, m.z, fmaf(x0.w, m.w, a0[r]))));
            a1[r] = fmaf(x1.x, m.x, fmaf(x1.y, m.y, fmaf(x1.z, m.z, fmaf(x1.w, m.w, a1[r]))));
        }
    }
    float* O = doV ? Vmem : Kmem;
#pragma unroll
    for (int r = 0; r < 8; ++r) {
        O[(size_t)(i0 + r) * DH_ + ep] = a0[r];
        O[(size_t)(i0 + r) * DH_ + ep + 32] = a1[r];
    }
}

// ---------------------------------------------------------------- k4: W1 partial projections (round-4 proven)
__global__ __launch_bounds__(128)
void k4_parts(const float* __restrict__ q, const float* __restrict__ kctx,
              const float* __restrict__ Kmem, const float* __restrict__ W1,
              float* __restrict__ qp, float* __restrict__ kcp, float* __restrict__ kmp)
{
    const int bid = blockIdx.x;
    const int tid = threadIdx.x;  // 128 = e
    const float* src; float* dst; int woff;
    if (bid < 1024)      { int r0 = bid * 4;          src = q    + (size_t)r0 * DH_; dst = qp  + (size_t)r0 * HID; woff = 0; }
    else if (bid < 2048) { int r0 = (bid - 1024) * 4; src = kctx + (size_t)r0 * DH_; dst = kcp + (size_t)r0 * HID; woff = DH_; }
    else                 { int r0 = (bid - 2048) * 4; src = Kmem + (size_t)r0 * DH_; dst = kmp + (size_t)r0 * HID; woff = DH_; }
    __shared__ float s[4][DH_];
    for (int l = tid; l < 4 * DH_; l += 128) s[l >> 6][l & 63] = src[l];
    __syncthreads();
    const float* wr = W1 + (size_t)tid * (2 * DH_) + woff;
    float a0 = 0.f, a1 = 0.f, a2 = 0.f, a3 = 0.f;
#pragma unroll 8
    for (int d = 0; d < DH_; ++d) {
        float w = wr[d];
        a0 = fmaf(s[0][d], w, a0);
        a1 = fmaf(s[1][d], w, a1);
        a2 = fmaf(s[2][d], w, a2);
        a3 = fmaf(s[3][d], w, a3);
    }
    dst[0 * HID + tid] = a0;
    dst[1 * HID + tid] = a1;
    dst[2 * HID + tid] = a2;
    dst[3 * HID + tid] = a3;
}

// ---------------------------------------------------------------- k5: MLP scores + softmax + weighted sum
__global__ __launch_bounds__(256)
void k5_attn(const float* __restrict__ qp, const float* __restrict__ kcp,
             const float* __restrict__ kmp, const float* __restrict__ vctx,
             const float* __restrict__ Vmem, const float* __restrict__ b1,
             const float* __restrict__ w2, const float* __restrict__ b2,
             float* __restrict__ out, float* __restrict__ outw)
{
    const int bid = blockIdx.x;
    const int t = bid & 127, h = (bid >> 7) & 7, b = bid >> 10;
    const int tid = threadIdx.x;
    const int lane = tid & 63, wv = tid >> 6;
    const int bh = b * H_ + h, bht = bh * TQ_ + t, bt = b * TQ_ + t;
    constexpr int NS = TK_ + TOPK;  // 160
    __shared__ float qps[HID], b1s[HID], w2s[HID];
    __shared__ float sc[NS];
    __shared__ float red[8];
    if (tid < HID) {
        qps[tid] = qp[(size_t)bht * HID + tid];
        b1s[tid] = b1[tid];
        w2s[tid] = w2[tid];
    }
    __syncthreads();
    const float bias2 = b2[0];
    if (tid < NS) {
        const float* kr = (tid < TK_) ? (kcp + ((size_t)bh * TK_ + tid) * HID)
                                      : (kmp + ((size_t)bt * TOPK + (tid - TK_)) * HID);
        float acc = 0.f;
#pragma unroll 4
        for (int e4 = 0; e4 < HID / 4; ++e4) {
            float4 kv = *reinterpret_cast<const float4*>(kr + e4 * 4);
            acc += fmaxf(qps[e4 * 4 + 0] + kv.x + b1s[e4 * 4 + 0], 0.f) * w2s[e4 * 4 + 0];
            acc += fmaxf(qps[e4 * 4 + 1] + kv.y + b1s[e4 * 4 + 1], 0.f) * w2s[e4 * 4 + 1];
            acc += fmaxf(qps[e4 * 4 + 2] + kv.z + b1s[e4 * 4 + 2], 0.f) * w2s[e4 * 4 + 2];
            acc += fmaxf(qps[e4 * 4 + 3] + kv.w + b1s[e4 * 4 + 3], 0.f) * w2s[e4 * 4 + 3];
        }
        sc[tid] = acc + bias2;
    }
    __syncthreads();
    float v = (tid < NS) ? sc[tid] : -INFINITY;
    float m = v;
#pragma unroll
    for (int off = 1; off < 64; off <<= 1) m = fmaxf(m, __shfl_xor(m, off));
    if (lane == 0) red[wv] = m;
    __syncthreads();
    if (tid == 0) red[4] = fmaxf(fmaxf(red[0], red[1]), fmaxf(red[2], red[3]));
    __syncthreads();
    const float mm = red[4];
    float e = (tid < NS) ? expf(v - mm) : 0.f;
    float ssum = e;
#pragma unroll
    for (int off = 1; off < 64; off <<= 1) ssum += __shfl_xor(ssum, off);
    if (lane == 0) red[wv] = ssum;
    __syncthreads();
    if (tid == 0) red[5] = red[0] + red[1] + red[2] + red[3];
    __syncthreads();
    const float inv = 1.f / red[5];
    if (tid < NS) {
        float w = e * inv;
        sc[tid] = w;
        outw[(size_t)bht * NS + tid] = w;
    }
    __syncthreads();
    if (tid < DH_) {
        float acc = 0.f;
        const float* vb = vctx + (size_t)bh * TK_ * DH_ + tid;
        for (int s2 = 0; s2 < TK_; ++s2) acc = fmaf(sc[s2], vb[(size_t)s2 * DH_], acc);
        const float* vm = Vmem + (size_t)bt * TOPK * DH_ + tid;
#pragma unroll
        for (int kk = 0; kk < TOPK; ++kk) acc = fmaf(sc[TK_ + kk], vm[(size_t)kk * DH_], acc);
        out[(size_t)bht * DH_ + tid] = acc;
    }
}

// ---------------------------------------------------------------- launch
extern "C" void kernel_launch(void* const* d_in, const int* in_sizes, int n_in,
                              void* d_out, int out_size, void* d_ws, size_t ws_size,
                              hipStream_t stream)
{
    const float* q    = (const float*)d_in[0];
    const float* kctx = (const float*)d_in[1];
    const float* vctx = (const float*)d_in[2];
    const float* qm   = (const float*)d_in[3];
    const float* mk   = (const float*)d_in[4];
    const float* mv   = (const float*)d_in[5];
    const float* Wk   = (const float*)d_in[6];
    const float* Wv   = (const float*)d_in[7];
    const float* W1   = (const float*)d_in[8];
    const float* b1   = (const float*)d_in[9];
    const float* w2   = (const float*)d_in[10];
    const float* b2   = (const float*)d_in[11];
    float* out  = (float*)d_out;
    float* outw = out + (size_t)B_ * H_ * TQ_ * DH_;

    char* w = (char*)d_ws;
    unsigned short* mkb = (unsigned short*)w; w += sizeof(unsigned short) * (size_t)NPAD * DM;
    unsigned short* qmb = (unsigned short*)w; w += sizeof(unsigned short) * R_ * DM;
    unsigned* cand_k = (unsigned*)w; w += sizeof(unsigned) * (size_t)R_ * NCAND;
    int*   cand_i = (int*)w;   w += sizeof(int) * (size_t)R_ * NCAND;
    int*   cand2_i= (int*)w;   w += sizeof(int) * R_ * CAP;
    int*   cand2_n= (int*)w;   w += sizeof(int) * R_;
    double* rsc   = (double*)w; w += sizeof(double) * R_ * CAP;
    int*   sel    = (int*)w;   w += sizeof(int) * R_ * TOPK;
    float* Kmem   = (float*)w; w += sizeof(float) * R_ * TOPK * DH_;
    float* Vmem   = (float*)w; w += sizeof(float) * R_ * TOPK * DH_;
    float* qp     = (float*)w; w += sizeof(float) * B_ * H_ * TQ_ * HID;
    float* kcp    = (float*)w; w += sizeof(float) * B_ * H_ * TK_ * HID;
    float* kmp    = (float*)w; w += sizeof(float) * R_ * TOPK * HID;

    hipLaunchKernelGGL(k0_cvt, dim3(4096), dim3(256), 0, stream, mk, qm, mkb);
    hipLaunchKernelGGL(k1_mfma, dim3(NCHP * 4), dim3(256), 0, stream, qmb, mkb, cand_k, cand_i);
    hipLaunchKernelGGL(k2a_thresh, dim3(R_), dim3(256), 0, stream, cand_k, cand_i, cand2_i, cand2_n);
    hipLaunchKernelGGL(k2b_rescore, dim3(R_, CAP / 4), dim3(256), 0, stream, qm, mk, cand2_i, cand2_n, rsc);
    hipLaunchKernelGGL(k2c_top32, dim3(R_), dim3(64), 0, stream, rsc, cand2_i, cand2_n, sel);
    hipLaunchKernelGGL(k3_proj, dim3(R_ * TOPK / 8), dim3(64), 0, stream, mk, mv, Wk, Wv, sel, Kmem, Vmem);
    hipLaunchKernelGGL(k4_parts, dim3(6144), dim3(128), 0, stream, q, kctx, Kmem, W1, qp, kcp, kmp);
    hipLaunchKernelGGL(k5_attn, dim3(B_ * H_ * TQ_), dim3(256), 0, stream, qp, kcp, kmp, vctx, Vmem, b1, w2, b2, out, outw);
}

// Round 9
// 364.149 us; speedup vs baseline: 1.0551x; 1.0432x over previous
//
#include <hip/hip_runtime.h>
#include <cmath>

constexpr int B_ = 4, H_ = 8, TQ_ = 128, TK_ = 128, DH_ = 64;
constexpr int NMEM = 100000, DM = 512, TOPK = 32, HID = 128;
constexpr int R_ = B_ * TQ_;                    // 512 memory rows (b,t)
constexpr int CTILE = 128, RTILE = 64;
constexpr int NCHP = 784;                       // padded chunk count (8 XCDs x 98)
constexpr int NPAD = NCHP * CTILE;              // 100352 padded rows
constexpr int KC = 16;                          // candidates kept per chunk
constexpr int NCAND = NCHP * KC;                // 12544 = 49*256
constexpr int KSEL = 48;                        // min rescored candidates
constexpr int CAP  = 128;                       // max rescored candidates
constexpr int NLD  = NCAND / 256;               // 49 keys per thread (exact)

using f32x4  = __attribute__((ext_vector_type(4))) float;
using bf16x8 = __attribute__((ext_vector_type(8))) short;
using u16x8  = __attribute__((ext_vector_type(8))) unsigned short;

#define GLOAD16(g, l) __builtin_amdgcn_global_load_lds( \
    (const __attribute__((address_space(1))) void*)(g), \
    (__attribute__((address_space(3))) void*)(l), 16, 0, 0)

static __device__ __forceinline__ unsigned short f2bf(float f) {
    unsigned u = __float_as_uint(f);
    u = (u + 0x7FFFu + ((u >> 16) & 1u)) >> 16;
    return (unsigned short)u;
}

// ---------------------------------------------------------------- k0: fp32 -> bf16 (mk padded + qm, one kernel)
__global__ __launch_bounds__(256)
void k0_cvt(const float* __restrict__ mk, const float* __restrict__ qm,
            unsigned short* __restrict__ dst)
{
    const long totalmk = (long)NPAD * DM;          // bf16 elements for mk region
    const long nvalid  = (long)NMEM * DM;
    const long total   = totalmk + (long)R_ * DM;
    long stride = (long)gridDim.x * 256 * 8;
    for (long base = ((long)blockIdx.x * 256 + threadIdx.x) * 8; base < total; base += stride) {
        u16x8 o;
        const float* src = nullptr;
        long off = 0;
        if (base < totalmk) {
            if (base < nvalid) { src = mk; off = base; }
        } else { src = qm; off = base - totalmk; }
        if (src) {
            float4 v0 = *reinterpret_cast<const float4*>(src + off);
            float4 v1 = *reinterpret_cast<const float4*>(src + off + 4);
            o[0] = f2bf(v0.x); o[1] = f2bf(v0.y); o[2] = f2bf(v0.z); o[3] = f2bf(v0.w);
            o[4] = f2bf(v1.x); o[5] = f2bf(v1.y); o[6] = f2bf(v1.z); o[7] = f2bf(v1.w);
        } else {
            o = (u16x8)0;
        }
        *reinterpret_cast<u16x8*>(dst + base) = o;
    }
}

// ---------------------------------------------------------------- k1: bf16 MFMA 64x128 tile + per-chunk top-16
__global__ __launch_bounds__(256)
void k1_mfma(const unsigned short* __restrict__ qmb, const unsigned short* __restrict__ mkb,
             unsigned* __restrict__ cand_k, int* __restrict__ cand_i)
{
    // XCD-aware decomposition: the 8 blocks sharing a chunk land consecutively
    // on the SAME XCD so the B tile is fetched into that XCD's L2 exactly once.
    const int wgid = blockIdx.x;          // 0..6271
    const int xcd = wgid & 7;
    const int k9 = wgid >> 3;             // 0..783
    const int chunk = xcd * 98 + (k9 >> 3);
    const int rt = k9 & 7;
    const int row0 = rt * RTILE;
    const int col0 = chunk * CTILE;
    const int tid = threadIdx.x;
    const int lane = tid & 63, w = tid >> 6;
    const int wm = w >> 1, wn = w & 1;    // wave computes 32x64

    // union: A[64][64]bf16 @0 (8 KiB) + B[128][64]bf16 @8192 (16 KiB)  |  sc[64][132] f32
    __shared__ __align__(16) char smem[64 * 132 * 4];
    char* Abase = smem;
    char* Bbase = smem + 8192;
    float* scf = (float*)smem;

    // hoisted staging source pointers (swizzled source, linear LDS dest)
    const char* srcA[2];
    const char* srcB[4];
#pragma unroll
    for (int p = 0; p < 2; ++p) {
        int X = p * 4096 + w * 1024 + lane * 16;
        int r = X >> 7, c = (X & 127) ^ ((r & 7) << 4);
        srcA[p] = (const char*)qmb + (size_t)(row0 + r) * 1024 + c;
    }
#pragma unroll
    for (int p = 0; p < 4; ++p) {
        int X = p * 4096 + w * 1024 + lane * 16;
        int r = X >> 7, c = (X & 127) ^ ((r & 7) << 4);
        srcB[p] = (const char*)mkb + (size_t)(col0 + r) * 1024 + c;
    }
    // hoisted LDS fragment byte-offsets
    int aoff[2][2], boff[4][2];
#pragma unroll
    for (int mi = 0; mi < 2; ++mi) {
        int rr = wm * 32 + mi * 16 + (lane & 15);
        int bse = rr * 128 + ((lane >> 4) * 16);
        aoff[mi][0] = bse ^ ((rr & 7) << 4);
        aoff[mi][1] = (bse + 64) ^ ((rr & 7) << 4);
    }
#pragma unroll
    for (int ni = 0; ni < 4; ++ni) {
        int rr = wn * 64 + ni * 16 + (lane & 15);
        int bse = rr * 128 + ((lane >> 4) * 16);
        boff[ni][0] = 8192 + (bse ^ ((rr & 7) << 4));
        boff[ni][1] = 8192 + ((bse + 64) ^ ((rr & 7) << 4));
    }

    f32x4 acc[2][4];
#pragma unroll
    for (int mi = 0; mi < 2; ++mi)
#pragma unroll
        for (int ni = 0; ni < 4; ++ni) acc[mi][ni] = (f32x4)0.f;

    for (int ks = 0; ks < 8; ++ks) {
#pragma unroll
        for (int p = 0; p < 2; ++p) {
            GLOAD16(srcA[p], Abase + p * 4096 + w * 1024);
            srcA[p] += 128;
        }
#pragma unroll
        for (int p = 0; p < 4; ++p) {
            GLOAD16(srcB[p], Bbase + p * 4096 + w * 1024);
            srcB[p] += 128;
        }
        __syncthreads();
#pragma unroll
        for (int kk = 0; kk < 2; ++kk) {
            bf16x8 af[2], bfr[4];
#pragma unroll
            for (int mi = 0; mi < 2; ++mi)
                af[mi] = *reinterpret_cast<const bf16x8*>(smem + aoff[mi][kk]);
#pragma unroll
            for (int ni = 0; ni < 4; ++ni)
                bfr[ni] = *reinterpret_cast<const bf16x8*>(smem + boff[ni][kk]);
#pragma unroll
            for (int mi = 0; mi < 2; ++mi)
#pragma unroll
                for (int ni = 0; ni < 4; ++ni)
                    acc[mi][ni] = __builtin_amdgcn_mfma_f32_16x16x32_bf16(af[mi], bfr[ni], acc[mi][ni], 0, 0, 0);
        }
        __syncthreads();
    }

    // scores -> LDS, PERMUTED within each row: pos = (cc&31)*4 + (cc>>5)
    // so a thread's 32-col slice {col : col%32 in [sub*8, sub*8+8)} is 8
    // contiguous float4 groups. C/D layout: col=lane&15, row=(lane>>4)*4+reg.
#pragma unroll
    for (int mi = 0; mi < 2; ++mi)
#pragma unroll
        for (int ni = 0; ni < 4; ++ni)
#pragma unroll
            for (int reg = 0; reg < 4; ++reg) {
                int rr = wm * 32 + mi * 16 + (lane >> 4) * 4 + reg;
                int cc = wn * 64 + ni * 16 + (lane & 15);
                int pos = ((cc & 31) << 2) | (cc >> 5);
                scf[rr * 132 + pos] = (col0 + cc < NMEM) ? acc[mi][ni][reg] : -INFINITY;
            }
    __syncthreads();

    // single-pass per-thread top-4, u32 keys (25-bit score | 7-bit 127-col),
    // 8 x ds_read_b128 per thread (4 threads per row)
    const int rid = tid >> 2, sub = tid & 3;
    const float* srow = scf + rid * 132 + sub * 32;
    const int bsub = 127 - sub * 8;
    unsigned t0 = 0u, t1 = 0u, t2 = 0u, t3 = 0u;
#pragma unroll
    for (int i = 0; i < 8; ++i) {
        float4 v4 = *reinterpret_cast<const float4*>(srow + i * 4);
        float vv[4] = {v4.x, v4.y, v4.z, v4.w};
#pragma unroll
        for (int q = 0; q < 4; ++q) {
            unsigned b = __float_as_uint(vv[q]);
            unsigned s = b ^ ((unsigned)((int)b >> 31) | 0x80000000u);   // order-preserving
            unsigned key = (s & 0xFFFFFF80u) | (unsigned)(bsub - (q * 32 + i));
            bool g0 = key > t0, g1 = key > t1, g2 = key > t2, g3 = key > t3;
            unsigned n0 = g0 ? key : t0;
            unsigned n1 = g0 ? t0 : (g1 ? key : t1);
            unsigned n2 = g1 ? t1 : (g2 ? key : t2);
            unsigned n3 = g2 ? t2 : (g3 ? key : t3);
            t0 = n0; t1 = n1; t2 = n2; t3 = n3;
        }
    }
    size_t base = (size_t)(row0 + rid) * NCAND + (size_t)chunk * KC + sub * 4;
    uint4 kv, iv;
    kv.x = t0; iv.x = col0 + 127 - (int)(t0 & 127u);
    kv.y = t1; iv.y = col0 + 127 - (int)(t1 & 127u);
    kv.z = t2; iv.z = col0 + 127 - (int)(t2 & 127u);
    kv.w = t3; iv.w = col0 + 127 - (int)(t3 & 127u);
    *reinterpret_cast<uint4*>(cand_k + base) = kv;
    *reinterpret_cast<uint4*>(cand_i + base) = iv;
}

// ---------------------------------------------------------------- k2a: threshold select (radix binary search) + gather
__global__ __launch_bounds__(256)
void k2a_thresh(const unsigned* __restrict__ cand_k, const int* __restrict__ cand_i,
                int* __restrict__ cand2_i, int* __restrict__ cand2_n)
{
    const int row = blockIdx.x;
    const int tid = threadIdx.x;
    const int lane = tid & 63, wv = tid >> 6;
    const unsigned* ck = cand_k + (size_t)row * NCAND;

    unsigned key[NLD];
#pragma unroll
    for (int j = 0; j < NLD; ++j) key[j] = ck[tid + j * 256];

    __shared__ int red[4];
    __shared__ int cnt;
    unsigned lo = 0u;
    int c_cur = NCAND;
    for (int bit = 31; bit >= 0; --bit) {
        if (c_cur <= CAP) break;   // uniform across block
        unsigned T = lo | (1u << bit);
        int c = 0;
#pragma unroll
        for (int j = 0; j < NLD; ++j) c += (key[j] >= T);
#pragma unroll
        for (int off = 1; off < 64; off <<= 1) c += __shfl_xor(c, off);
        if (lane == 0) red[wv] = c;
        __syncthreads();
        int ct = red[0] + red[1] + red[2] + red[3];
        if (ct >= KSEL) { lo = T; c_cur = ct; }
        __syncthreads();
    }

    if (tid == 0) cnt = 0;
    __syncthreads();
#pragma unroll
    for (int j = 0; j < NLD; ++j) {
        if (key[j] >= lo) {
            int p = atomicAdd(&cnt, 1);
            if (p < CAP) cand2_i[(size_t)row * CAP + p] = cand_i[(size_t)row * NCAND + tid + j * 256];
        }
    }
    __syncthreads();
    if (tid == 0) cand2_n[row] = cnt < CAP ? cnt : CAP;
}

// ---------------------------------------------------------------- k2b: fp64 rescore (one wave per candidate, float4 loads)
__global__ __launch_bounds__(256)
void k2b_rescore(const float* __restrict__ qm, const float* __restrict__ mk,
                 const int* __restrict__ cand2_i, const int* __restrict__ cand2_n,
                 double* __restrict__ rsc)
{
    const int row = blockIdx.x;
    const int tid = threadIdx.x;
    const int lane = tid & 63, wv = tid >> 6;
    const int c = blockIdx.y * 4 + wv;
    const int n = cand2_n[row];
    if (c >= n) return;
    const int idx = cand2_i[(size_t)row * CAP + c];
    const float4* q4 = reinterpret_cast<const float4*>(qm + (size_t)row * DM);
    const float4* k4 = reinterpret_cast<const float4*>(mk + (size_t)idx * DM);
    float4 a0 = q4[lane], b0 = k4[lane];
    float4 a1 = q4[lane + 64], b1 = k4[lane + 64];
    double p = (double)a0.x * b0.x + (double)a0.y * b0.y
             + (double)a0.z * b0.z + (double)a0.w * b0.w
             + (double)a1.x * b1.x + (double)a1.y * b1.y
             + (double)a1.z * b1.z + (double)a1.w * b1.w;
#pragma unroll
    for (int off = 1; off < 64; off <<= 1) p += __shfl_xor(p, off);
    if (lane == 0) rsc[(size_t)row * CAP + c] = p;
}

// ---------------------------------------------------------------- k2c: exact ordered top-32 (one wave per row)
__global__ __launch_bounds__(64)
void k2c_top32(const double* __restrict__ rsc, const int* __restrict__ cand2_i,
               const int* __restrict__ cand2_n, int* __restrict__ sel)
{
    const int row = blockIdx.x;
    const int lane = threadIdx.x;
    const int n = cand2_n[row];
    double v0 = -1.0e300, v1 = -1.0e300;
    int i0 = 0x7fffffff, i1 = 0x7fffffff;
    if (lane < n)      { v0 = rsc[(size_t)row * CAP + lane];      i0 = cand2_i[(size_t)row * CAP + lane]; }
    if (lane + 64 < n) { v1 = rsc[(size_t)row * CAP + lane + 64]; i1 = cand2_i[(size_t)row * CAP + lane + 64]; }
    for (int s = 0; s < TOPK; ++s) {
        double bv; int bi;
        if (v0 > v1 || (v0 == v1 && i0 < i1)) { bv = v0; bi = i0; }
        else                                  { bv = v1; bi = i1; }
#pragma unroll
        for (int off = 1; off < 64; off <<= 1) {
            double ov = __shfl_xor(bv, off);
            int    oi = __shfl_xor(bi, off);
            if (ov > bv || (ov == bv && oi < bi)) { bv = ov; bi = oi; }
        }
        if (lane == 0) sel[row * TOPK + s] = bi;
        if (i0 == bi) v0 = -1.0e300;
        if (i1 == bi) v1 = -1.0e300;
    }
}

// ---------------------------------------------------------------- k3: gather + Wk/Wv projection (128 threads)
__global__ __launch_bounds__(128)
void k3_proj(const float* __restrict__ mk, const float* __restrict__ mv,
             const float* __restrict__ Wk, const float* __restrict__ Wv,
             const int* __restrict__ sel,
             float* __restrict__ Kmem, float* __restrict__ Vmem)
{
    const int i0 = blockIdx.x * 8;   // pair base, pair = row*TOPK+k (16384 total)
    const int tid = threadIdx.x;     // 128
    __shared__ float s[2][8][DM];    // [mat][row][d] 32 KiB
    __shared__ int si[8];
    if (tid < 8) si[tid] = sel[i0 + tid];
    __syncthreads();
    for (int l = tid; l < 2048; l += 128) {   // 2 mats x 8 rows x 128 float4
        int mat = l >> 10, r = (l >> 7) & 7, c4 = l & 127;
        const float* src = (mat ? mv : mk) + (size_t)si[r] * DM + c4 * 4;
        *reinterpret_cast<float4*>(&s[mat][r][c4 * 4]) =
            *reinterpret_cast<const float4*>(src);
    }
    __syncthreads();
    const int doV = tid >> 6;        // 0: K path, 1: V path
    const int ep = tid & 63;         // output element
    const float* w0 = (doV ? Wv : Wk) + (size_t)ep * DM;
    float a0[8];
#pragma unroll
    for (int r = 0; r < 8; ++r) a0[r] = 0.f;
    for (int d4 = 0; d4 < DM / 4; ++d4) {
        float4 x0 = *reinterpret_cast<const float4*>(w0 + d4 * 4);
#pragma unroll
        for (int r = 0; r < 8; ++r) {
            float4 m = *reinterpret_cast<const float4*>(&s[doV][r][d4 * 4]);
            a0[r] = fmaf(x0.x, m.x, fmaf(x0.y, m.y, fmaf(x0.z, m.z, fmaf(x0.w, m.w, a0[r]))));
        }
    }
    float* O = doV ? Vmem : Kmem;
#pragma unroll
    for (int r = 0; r < 8; ++r)
        O[(size_t)(i0 + r) * DH_ + ep] = a0[r];
}

// ---------------------------------------------------------------- k4: W1 partial projections
__global__ __launch_bounds__(128)
void k4_parts(const float* __restrict__ q, const float* __restrict__ kctx,
              const float* __restrict__ Kmem, const float* __restrict__ W1,
              float* __restrict__ qp, float* __restrict__ kcp, float* __restrict__ kmp)
{
    const int bid = blockIdx.x;
    const int tid = threadIdx.x;  // 128 = e
    const float* src; float* dst; int woff;
    if (bid < 1024)      { int r0 = bid * 4;          src = q    + (size_t)r0 * DH_; dst = qp  + (size_t)r0 * HID; woff = 0; }
    else if (bid < 2048) { int r0 = (bid - 1024) * 4; src = kctx + (size_t)r0 * DH_; dst = kcp + (size_t)r0 * HID; woff = DH_; }
    else                 { int r0 = (bid - 2048) * 4; src = Kmem + (size_t)r0 * DH_; dst = kmp + (size_t)r0 * HID; woff = DH_; }
    __shared__ float s[4][DH_];
    for (int l = tid; l < 4 * DH_; l += 128) s[l >> 6][l & 63] = src[l];
    __syncthreads();
    const float* wr = W1 + (size_t)tid * (2 * DH_) + woff;
    float a0 = 0.f, a1 = 0.f, a2 = 0.f, a3 = 0.f;
#pragma unroll 8
    for (int d = 0; d < DH_; ++d) {
        float w = wr[d];
        a0 = fmaf(s[0][d], w, a0);
        a1 = fmaf(s[1][d], w, a1);
        a2 = fmaf(s[2][d], w, a2);
        a3 = fmaf(s[3][d], w, a3);
    }
    dst[0 * HID + tid] = a0;
    dst[1 * HID + tid] = a1;
    dst[2 * HID + tid] = a2;
    dst[3 * HID + tid] = a3;
}

// ---------------------------------------------------------------- k5: MLP scores + softmax + weighted sum (PV split)
__global__ __launch_bounds__(256)
void k5_attn(const float* __restrict__ qp, const float* __restrict__ kcp,
             const float* __restrict__ kmp, const float* __restrict__ vctx,
             const float* __restrict__ Vmem, const float* __restrict__ b1,
             const float* __restrict__ w2, const float* __restrict__ b2,
             float* __restrict__ out, float* __restrict__ outw)
{
    const int bid = blockIdx.x;
    const int t = bid & 127, h = (bid >> 7) & 7, b = bid >> 10;
    const int tid = threadIdx.x;
    const int lane = tid & 63, wv = tid >> 6;
    const int bh = b * H_ + h, bht = bh * TQ_ + t, bt = b * TQ_ + t;
    constexpr int NS = TK_ + TOPK;  // 160
    __shared__ float qps[HID], b1s[HID], w2s[HID];
    __shared__ float sc[NS];
    __shared__ float red[8];
    __shared__ float part[4][DH_];
    if (tid < HID) {
        qps[tid] = qp[(size_t)bht * HID + tid];
        b1s[tid] = b1[tid];
        w2s[tid] = w2[tid];
    }
    __syncthreads();
    const float bias2 = b2[0];
    if (tid < NS) {
        const float* kr = (tid < TK_) ? (kcp + ((size_t)bh * TK_ + tid) * HID)
                                      : (kmp + ((size_t)bt * TOPK + (tid - TK_)) * HID);
        float acc = 0.f;
#pragma unroll 4
        for (int e4 = 0; e4 < HID / 4; ++e4) {
            float4 kv = *reinterpret_cast<const float4*>(kr + e4 * 4);
            acc += fmaxf(qps[e4 * 4 + 0] + kv.x + b1s[e4 * 4 + 0], 0.f) * w2s[e4 * 4 + 0];
            acc += fmaxf(qps[e4 * 4 + 1] + kv.y + b1s[e4 * 4 + 1], 0.f) * w2s[e4 * 4 + 1];
            acc += fmaxf(qps[e4 * 4 + 2] + kv.z + b1s[e4 * 4 + 2], 0.f) * w2s[e4 * 4 + 2];
            acc += fmaxf(qps[e4 * 4 + 3] + kv.w + b1s[e4 * 4 + 3], 0.f) * w2s[e4 * 4 + 3];
        }
        sc[tid] = acc + bias2;
    }
    __syncthreads();
    float v = (tid < NS) ? sc[tid] : -INFINITY;
    float m = v;
#pragma unroll
    for (int off = 1; off < 64; off <<= 1) m = fmaxf(m, __shfl_xor(m, off));
    if (lane == 0) red[wv] = m;
    __syncthreads();
    if (tid == 0) red[4] = fmaxf(fmaxf(red[0], red[1]), fmaxf(red[2], red[3]));
    __syncthreads();
    const float mm = red[4];
    float e = (tid < NS) ? expf(v - mm) : 0.f;
    float ssum = e;
#pragma unroll
    for (int off = 1; off < 64; off <<= 1) ssum += __shfl_xor(ssum, off);
    if (lane == 0) red[wv] = ssum;
    __syncthreads();
    if (tid == 0) red[5] = red[0] + red[1] + red[2] + red[3];
    __syncthreads();
    const float inv = 1.f / red[5];
    if (tid < NS) {
        float w = e * inv;
        sc[tid] = w;
        outw[(size_t)bht * NS + tid] = w;
    }
    __syncthreads();
    // PV: each wave handles 40 s-values for all 64 dims
    {
        const int d = lane;
        const int s0 = wv * 40;
        float acc = 0.f;
        for (int s2 = s0; s2 < s0 + 40; ++s2) {
            const float* vrow = (s2 < TK_)
                ? (vctx + ((size_t)bh * TK_ + s2) * DH_)
                : (Vmem + ((size_t)bt * TOPK + (s2 - TK_)) * DH_);
            acc = fmaf(sc[s2], vrow[d], acc);
        }
        part[wv][d] = acc;
    }
    __syncthreads();
    if (tid < DH_)
        out[(size_t)bht * DH_ + tid] = part[0][tid] + part[1][tid] + part[2][tid] + part[3][tid];
}

// ---------------------------------------------------------------- launch
extern "C" void kernel_launch(void* const* d_in, const int* in_sizes, int n_in,
                              void* d_out, int out_size, void* d_ws, size_t ws_size,
                              hipStream_t stream)
{
    const float* q    = (const float*)d_in[0];
    const float* kctx = (const float*)d_in[1];
    const float* vctx = (const float*)d_in[2];
    const float* qm   = (const float*)d_in[3];
    const float* mk   = (const float*)d_in[4];
    const float* mv   = (const float*)d_in[5];
    const float* Wk   = (const float*)d_in[6];
    const float* Wv   = (const float*)d_in[7];
    const float* W1   = (const float*)d_in[8];
    const float* b1   = (const float*)d_in[9];
    const float* w2   = (const float*)d_in[10];
    const float* b2   = (const float*)d_in[11];
    float* out  = (float*)d_out;
    float* outw = out + (size_t)B_ * H_ * TQ_ * DH_;

    char* w = (char*)d_ws;
    unsigned short* mkb = (unsigned short*)w; w += sizeof(unsigned short) * (size_t)NPAD * DM;
    unsigned short* qmb = (unsigned short*)w; w += sizeof(unsigned short) * R_ * DM;
    unsigned* cand_k = (unsigned*)w; w += sizeof(unsigned) * (size_t)R_ * NCAND;
    int*   cand_i = (int*)w;   w += sizeof(int) * (size_t)R_ * NCAND;
    int*   cand2_i= (int*)w;   w += sizeof(int) * R_ * CAP;
    int*   cand2_n= (int*)w;   w += sizeof(int) * R_;
    double* rsc   = (double*)w; w += sizeof(double) * R_ * CAP;
    int*   sel    = (int*)w;   w += sizeof(int) * R_ * TOPK;
    float* Kmem   = (float*)w; w += sizeof(float) * R_ * TOPK * DH_;
    float* Vmem   = (float*)w; w += sizeof(float) * R_ * TOPK * DH_;
    float* qp     = (float*)w; w += sizeof(float) * B_ * H_ * TQ_ * HID;
    float* kcp    = (float*)w; w += sizeof(float) * B_ * H_ * TK_ * HID;
    float* kmp    = (float*)w; w += sizeof(float) * R_ * TOPK * HID;

    hipLaunchKernelGGL(k0_cvt, dim3(4096), dim3(256), 0, stream, mk, qm, mkb);
    hipLaunchKernelGGL(k1_mfma, dim3(NCHP * 8), dim3(256), 0, stream, qmb, mkb, cand_k, cand_i);
    hipLaunchKernelGGL(k2a_thresh, dim3(R_), dim3(256), 0, stream, cand_k, cand_i, cand2_i, cand2_n);
    hipLaunchKernelGGL(k2b_rescore, dim3(R_, CAP / 4), dim3(256), 0, stream, qm, mk, cand2_i, cand2_n, rsc);
    hipLaunchKernelGGL(k2c_top32, dim3(R_), dim3(64), 0, stream, rsc, cand2_i, cand2_n, sel);
    hipLaunchKernelGGL(k3_proj, dim3(R_ * TOPK / 8), dim3(128), 0, stream, mk, mv, Wk, Wv, sel, Kmem, Vmem);
    hipLaunchKernelGGL(k4_parts, dim3(6144), dim3(128), 0, stream, q, kctx, Kmem, W1, qp, kcp, kmp);
    hipLaunchKernelGGL(k5_attn, dim3(B_ * H_ * TQ_), dim3(256), 0, stream, qp, kcp, kmp, vctx, Vmem, b1, w2, b2, out, outw);
}

// Round 10
// 361.919 us; speedup vs baseline: 1.0616x; 1.0062x over previous
//
#include <hip/hip_runtime.h>
#include <cmath>

constexpr int B_ = 4, H_ = 8, TQ_ = 128, TK_ = 128, DH_ = 64;
constexpr int NMEM = 100000, DM = 512, TOPK = 32, HID = 128;
constexpr int R_ = B_ * TQ_;                    // 512 memory rows (b,t)
constexpr int CTILE = 128, RTILE = 128;         // 128x128 output tile
constexpr int NCHP = 784;                       // padded chunk count (8 XCDs x 98)
constexpr int NPAD = NCHP * CTILE;              // 100352 padded rows
constexpr int KC = 16;                          // candidates kept per chunk
constexpr int NCAND = NCHP * KC;                // 12544 = 49*256
constexpr int KSEL = 48;                        // min rescored candidates
constexpr int CAP  = 128;                       // max rescored candidates
constexpr int NLD  = NCAND / 256;               // 49 keys per thread (exact)

using f32x4  = __attribute__((ext_vector_type(4))) float;
using bf16x8 = __attribute__((ext_vector_type(8))) short;
using u16x8  = __attribute__((ext_vector_type(8))) unsigned short;

#define GLOAD16(g, l) __builtin_amdgcn_global_load_lds( \
    (const __attribute__((address_space(1))) void*)(g), \
    (__attribute__((address_space(3))) void*)(l), 16, 0, 0)

static __device__ __forceinline__ unsigned short f2bf(float f) {
    unsigned u = __float_as_uint(f);
    u = (u + 0x7FFFu + ((u >> 16) & 1u)) >> 16;
    return (unsigned short)u;
}

// ---------------------------------------------------------------- k0: fp32 -> bf16 (mk padded + qm, one kernel)
__global__ __launch_bounds__(256)
void k0_cvt(const float* __restrict__ mk, const float* __restrict__ qm,
            unsigned short* __restrict__ dst)
{
    const long totalmk = (long)NPAD * DM;          // bf16 elements for mk region
    const long nvalid  = (long)NMEM * DM;
    const long total   = totalmk + (long)R_ * DM;
    long stride = (long)gridDim.x * 256 * 8;
    for (long base = ((long)blockIdx.x * 256 + threadIdx.x) * 8; base < total; base += stride) {
        u16x8 o;
        const float* src = nullptr;
        long off = 0;
        if (base < totalmk) {
            if (base < nvalid) { src = mk; off = base; }
        } else { src = qm; off = base - totalmk; }
        if (src) {
            float4 v0 = *reinterpret_cast<const float4*>(src + off);
            float4 v1 = *reinterpret_cast<const float4*>(src + off + 4);
            o[0] = f2bf(v0.x); o[1] = f2bf(v0.y); o[2] = f2bf(v0.z); o[3] = f2bf(v0.w);
            o[4] = f2bf(v1.x); o[5] = f2bf(v1.y); o[6] = f2bf(v1.z); o[7] = f2bf(v1.w);
        } else {
            o = (u16x8)0;
        }
        *reinterpret_cast<u16x8*>(dst + base) = o;
    }
}

// ---------------------------------------------------------------- k1: bf16 MFMA 128x128 tile + per-chunk top-16
__global__ __launch_bounds__(256)
void k1_mfma(const unsigned short* __restrict__ qmb, const unsigned short* __restrict__ mkb,
             unsigned* __restrict__ cand_k)
{
    // XCD-aware decomposition: the 4 blocks sharing a chunk land consecutively
    // on the SAME XCD so the B tile is fetched into that XCD's L2 exactly once.
    const int wgid = blockIdx.x;          // 0..3135
    const int xcd = wgid & 7;
    const int k9 = wgid >> 3;             // 0..391
    const int chunk = xcd * 98 + (k9 >> 2);
    const int rt = k9 & 3;
    const int row0 = rt * RTILE;
    const int col0 = chunk * CTILE;
    const int tid = threadIdx.x;
    const int lane = tid & 63, w = tid >> 6;
    const int wm = w >> 1, wn = w & 1;    // wave computes 64x64

    // LDS: A[128][64]bf16 @0 (16 KiB) + B[128][64]bf16 @16384 (16 KiB)
    //      union with selection scratch sc[64][132] f32 (33792 B)
    __shared__ __align__(16) char smem[64 * 132 * 4];
    char* Abase = smem;
    char* Bbase = smem + 16384;
    float* scf = (float*)smem;

    // hoisted staging source pointers (swizzled source, linear LDS dest)
    const char* srcA[4];
    const char* srcB[4];
#pragma unroll
    for (int p = 0; p < 4; ++p) {
        int X = p * 4096 + w * 1024 + lane * 16;
        int r = X >> 7, c = (X & 127) ^ ((r & 7) << 4);
        srcA[p] = (const char*)qmb + (size_t)(row0 + r) * 1024 + c;
        srcB[p] = (const char*)mkb + (size_t)(col0 + r) * 1024 + c;
    }
    // hoisted LDS fragment byte-offsets
    int aoff[4][2], boff[4][2];
#pragma unroll
    for (int mi = 0; mi < 4; ++mi) {
        int rr = wm * 64 + mi * 16 + (lane & 15);
        int bse = rr * 128 + ((lane >> 4) * 16);
        aoff[mi][0] = bse ^ ((rr & 7) << 4);
        aoff[mi][1] = (bse + 64) ^ ((rr & 7) << 4);
    }
#pragma unroll
    for (int ni = 0; ni < 4; ++ni) {
        int rr = wn * 64 + ni * 16 + (lane & 15);
        int bse = rr * 128 + ((lane >> 4) * 16);
        boff[ni][0] = 16384 + (bse ^ ((rr & 7) << 4));
        boff[ni][1] = 16384 + ((bse + 64) ^ ((rr & 7) << 4));
    }

    f32x4 acc[4][4];
#pragma unroll
    for (int mi = 0; mi < 4; ++mi)
#pragma unroll
        for (int ni = 0; ni < 4; ++ni) acc[mi][ni] = (f32x4)0.f;

    for (int ks = 0; ks < 8; ++ks) {
#pragma unroll
        for (int p = 0; p < 4; ++p) {
            GLOAD16(srcA[p], Abase + p * 4096 + w * 1024);
            srcA[p] += 128;
            GLOAD16(srcB[p], Bbase + p * 4096 + w * 1024);
            srcB[p] += 128;
        }
        __syncthreads();
#pragma unroll
        for (int kk = 0; kk < 2; ++kk) {
            bf16x8 af[4], bfr[4];
#pragma unroll
            for (int mi = 0; mi < 4; ++mi)
                af[mi] = *reinterpret_cast<const bf16x8*>(smem + aoff[mi][kk]);
#pragma unroll
            for (int ni = 0; ni < 4; ++ni)
                bfr[ni] = *reinterpret_cast<const bf16x8*>(smem + boff[ni][kk]);
#pragma unroll
            for (int mi = 0; mi < 4; ++mi)
#pragma unroll
                for (int ni = 0; ni < 4; ++ni)
                    acc[mi][ni] = __builtin_amdgcn_mfma_f32_16x16x32_bf16(af[mi], bfr[ni], acc[mi][ni], 0, 0, 0);
        }
        __syncthreads();
    }

    // selection in two row-halves; sc[64][132] unions with staging LDS.
    // scores stored PERMUTED within each row: pos = (cc&31)*4 + (cc>>5) so a
    // thread's 32-col slice is 8 contiguous float4 groups.
    const int rid = tid >> 2, sub = tid & 3;
    const int bsub = 127 - sub * 8;
#pragma unroll
    for (int h = 0; h < 2; ++h) {
        if (wm == h) {
            // C/D layout: col=lane&15, row=(lane>>4)*4+reg
#pragma unroll
            for (int mi = 0; mi < 4; ++mi)
#pragma unroll
                for (int ni = 0; ni < 4; ++ni)
#pragma unroll
                    for (int reg = 0; reg < 4; ++reg) {
                        int rr = mi * 16 + (lane >> 4) * 4 + reg;      // 0..63 local
                        int cc = wn * 64 + ni * 16 + (lane & 15);
                        int pos = ((cc & 31) << 2) | (cc >> 5);
                        scf[rr * 132 + pos] = (col0 + cc < NMEM) ? acc[mi][ni][reg] : -INFINITY;
                    }
        }
        __syncthreads();

        // single-pass per-thread top-4, u32 keys (25-bit score | 7-bit 127-col)
        const float* srow = scf + rid * 132 + sub * 32;
        unsigned t0 = 0u, t1 = 0u, t2 = 0u, t3 = 0u;
#pragma unroll
        for (int i = 0; i < 8; ++i) {
            float4 v4 = *reinterpret_cast<const float4*>(srow + i * 4);
            float vv[4] = {v4.x, v4.y, v4.z, v4.w};
#pragma unroll
            for (int q = 0; q < 4; ++q) {
                unsigned b = __float_as_uint(vv[q]);
                unsigned s = b ^ ((unsigned)((int)b >> 31) | 0x80000000u);   // order-preserving
                unsigned key = (s & 0xFFFFFF80u) | (unsigned)(bsub - (q * 32 + i));
                bool g0 = key > t0, g1 = key > t1, g2 = key > t2, g3 = key > t3;
                unsigned n0 = g0 ? key : t0;
                unsigned n1 = g0 ? t0 : (g1 ? key : t1);
                unsigned n2 = g1 ? t1 : (g2 ? key : t2);
                unsigned n3 = g2 ? t2 : (g3 ? key : t3);
                t0 = n0; t1 = n1; t2 = n2; t3 = n3;
            }
        }
        size_t base = (size_t)(row0 + h * 64 + rid) * NCAND + (size_t)chunk * KC + sub * 4;
        *reinterpret_cast<uint4*>(cand_k + base) = make_uint4(t0, t1, t2, t3);
        __syncthreads();
    }
}

// ---------------------------------------------------------------- k2a: threshold select + gather (indices derived from keys)
__global__ __launch_bounds__(256)
void k2a_thresh(const unsigned* __restrict__ cand_k,
                int* __restrict__ cand2_i, int* __restrict__ cand2_n)
{
    const int row = blockIdx.x;
    const int tid = threadIdx.x;
    const int lane = tid & 63, wv = tid >> 6;
    const unsigned* ck = cand_k + (size_t)row * NCAND;

    unsigned key[NLD];
#pragma unroll
    for (int j = 0; j < NLD; ++j) key[j] = ck[tid + j * 256];

    __shared__ int red[4];
    __shared__ int cnt;
    unsigned lo = 0u;
    int c_cur = NCAND;
    for (int bit = 31; bit >= 0; --bit) {
        if (c_cur <= CAP) break;   // uniform across block
        unsigned T = lo | (1u << bit);
        int c = 0;
#pragma unroll
        for (int j = 0; j < NLD; ++j) c += (key[j] >= T);
#pragma unroll
        for (int off = 1; off < 64; off <<= 1) c += __shfl_xor(c, off);
        if (lane == 0) red[wv] = c;
        __syncthreads();
        int ct = red[0] + red[1] + red[2] + red[3];
        if (ct >= KSEL) { lo = T; c_cur = ct; }
        __syncthreads();
    }

    if (tid == 0) cnt = 0;
    __syncthreads();
#pragma unroll
    for (int j = 0; j < NLD; ++j) {
        if (key[j] >= lo) {
            int p = atomicAdd(&cnt, 1);
            if (p < CAP) {
                int ipos = tid + j * 256;
                int chunk = ipos >> 4;                      // /KC
                int col = (chunk << 7) + 127 - (int)(key[j] & 127u);
                cand2_i[(size_t)row * CAP + p] = col;
            }
        }
    }
    __syncthreads();
    if (tid == 0) cand2_n[row] = cnt < CAP ? cnt : CAP;
}

// ---------------------------------------------------------------- k2b: fp64 rescore (one wave per candidate, float4 loads)
__global__ __launch_bounds__(256)
void k2b_rescore(const float* __restrict__ qm, const float* __restrict__ mk,
                 const int* __restrict__ cand2_i, const int* __restrict__ cand2_n,
                 double* __restrict__ rsc)
{
    const int row = blockIdx.x;
    const int tid = threadIdx.x;
    const int lane = tid & 63, wv = tid >> 6;
    const int c = blockIdx.y * 4 + wv;
    const int n = cand2_n[row];
    if (c >= n) return;
    const int idx = cand2_i[(size_t)row * CAP + c];
    const float4* q4 = reinterpret_cast<const float4*>(qm + (size_t)row * DM);
    const float4* k4 = reinterpret_cast<const float4*>(mk + (size_t)idx * DM);
    float4 a0 = q4[lane], b0 = k4[lane];
    float4 a1 = q4[lane + 64], b1 = k4[lane + 64];
    double p = (double)a0.x * b0.x + (double)a0.y * b0.y
             + (double)a0.z * b0.z + (double)a0.w * b0.w
             + (double)a1.x * b1.x + (double)a1.y * b1.y
             + (double)a1.z * b1.z + (double)a1.w * b1.w;
#pragma unroll
    for (int off = 1; off < 64; off <<= 1) p += __shfl_xor(p, off);
    if (lane == 0) rsc[(size_t)row * CAP + c] = p;
}

// ---------------------------------------------------------------- k2c: exact ordered top-32 (one wave per row)
__global__ __launch_bounds__(64)
void k2c_top32(const double* __restrict__ rsc, const int* __restrict__ cand2_i,
               const int* __restrict__ cand2_n, int* __restrict__ sel)
{
    const int row = blockIdx.x;
    const int lane = threadIdx.x;
    const int n = cand2_n[row];
    double v0 = -1.0e300, v1 = -1.0e300;
    int i0 = 0x7fffffff, i1 = 0x7fffffff;
    if (lane < n)      { v0 = rsc[(size_t)row * CAP + lane];      i0 = cand2_i[(size_t)row * CAP + lane]; }
    if (lane + 64 < n) { v1 = rsc[(size_t)row * CAP + lane + 64]; i1 = cand2_i[(size_t)row * CAP + lane + 64]; }
    for (int s = 0; s < TOPK; ++s) {
        double bv; int bi;
        if (v0 > v1 || (v0 == v1 && i0 < i1)) { bv = v0; bi = i0; }
        else                                  { bv = v1; bi = i1; }
#pragma unroll
        for (int off = 1; off < 64; off <<= 1) {
            double ov = __shfl_xor(bv, off);
            int    oi = __shfl_xor(bi, off);
            if (ov > bv || (ov == bv && oi < bi)) { bv = ov; bi = oi; }
        }
        if (lane == 0) sel[row * TOPK + s] = bi;
        if (i0 == bi) v0 = -1.0e300;
        if (i1 == bi) v1 = -1.0e300;
    }
}

// ---------------------------------------------------------------- k3: gather + Wk/Wv projection + fused kmp
__global__ __launch_bounds__(128)
void k3_proj(const float* __restrict__ mk, const float* __restrict__ mv,
             const float* __restrict__ Wk, const float* __restrict__ Wv,
             const float* __restrict__ W1, const int* __restrict__ sel,
             float* __restrict__ kmp, float* __restrict__ Vmem)
{
    const int i0 = blockIdx.x * 8;   // pair base, pair = row*TOPK+k (16384 total)
    const int tid = threadIdx.x;     // 128
    __shared__ float s[2][8][DM];    // [mat][row][d] 32 KiB
    __shared__ float sKm[8][DH_];    // projected K rows, 2 KiB
    __shared__ int si[8];
    if (tid < 8) si[tid] = sel[i0 + tid];
    __syncthreads();
    for (int l = tid; l < 2048; l += 128) {   // 2 mats x 8 rows x 128 float4
        int mat = l >> 10, r = (l >> 7) & 7, c4 = l & 127;
        const float* src = (mat ? mv : mk) + (size_t)si[r] * DM + c4 * 4;
        *reinterpret_cast<float4*>(&s[mat][r][c4 * 4]) =
            *reinterpret_cast<const float4*>(src);
    }
    __syncthreads();
    const int doV = tid >> 6;        // 0: K path, 1: V path
    const int ep = tid & 63;         // output element
    const float* w0 = (doV ? Wv : Wk) + (size_t)ep * DM;
    float a0[8];
#pragma unroll
    for (int r = 0; r < 8; ++r) a0[r] = 0.f;
    for (int d4 = 0; d4 < DM / 4; ++d4) {
        float4 x0 = *reinterpret_cast<const float4*>(w0 + d4 * 4);
#pragma unroll
        for (int r = 0; r < 8; ++r) {
            float4 m = *reinterpret_cast<const float4*>(&s[doV][r][d4 * 4]);
            a0[r] = fmaf(x0.x, m.x, fmaf(x0.y, m.y, fmaf(x0.z, m.z, fmaf(x0.w, m.w, a0[r]))));
        }
    }
    if (doV) {
#pragma unroll
        for (int r = 0; r < 8; ++r)
            Vmem[(size_t)(i0 + r) * DH_ + ep] = a0[r];
    } else {
#pragma unroll
        for (int r = 0; r < 8; ++r)
            sKm[r][ep] = a0[r];
    }
    __syncthreads();
    // kmp[e] for the 8 rows: e = tid (0..127), W1k row = W1[e][DH_:2*DH_]
    const float* wr = W1 + (size_t)tid * (2 * DH_) + DH_;
    float acc[8];
#pragma unroll
    for (int r = 0; r < 8; ++r) acc[r] = 0.f;
#pragma unroll 8
    for (int d = 0; d < DH_; ++d) {
        float wv2 = wr[d];
#pragma unroll
        for (int r = 0; r < 8; ++r)
            acc[r] = fmaf(sKm[r][d], wv2, acc[r]);
    }
#pragma unroll
    for (int r = 0; r < 8; ++r)
        kmp[(size_t)(i0 + r) * HID + tid] = acc[r];
}

// ---------------------------------------------------------------- k4: W1 partial projections (q, kctx only)
__global__ __launch_bounds__(128)
void k4_parts(const float* __restrict__ q, const float* __restrict__ kctx,
              const float* __restrict__ W1,
              float* __restrict__ qp, float* __restrict__ kcp)
{
    const int bid = blockIdx.x;
    const int tid = threadIdx.x;  // 128 = e
    const float* src; float* dst; int woff;
    if (bid < 1024)      { int r0 = bid * 4;          src = q    + (size_t)r0 * DH_; dst = qp  + (size_t)r0 * HID; woff = 0; }
    else                 { int r0 = (bid - 1024) * 4; src = kctx + (size_t)r0 * DH_; dst = kcp + (size_t)r0 * HID; woff = DH_; }
    __shared__ float s[4][DH_];
    for (int l = tid; l < 4 * DH_; l += 128) s[l >> 6][l & 63] = src[l];
    __syncthreads();
    const float* wr = W1 + (size_t)tid * (2 * DH_) + woff;
    float a0 = 0.f, a1 = 0.f, a2 = 0.f, a3 = 0.f;
#pragma unroll 8
    for (int d = 0; d < DH_; ++d) {
        float w = wr[d];
        a0 = fmaf(s[0][d], w, a0);
        a1 = fmaf(s[1][d], w, a1);
        a2 = fmaf(s[2][d], w, a2);
        a3 = fmaf(s[3][d], w, a3);
    }
    dst[0 * HID + tid] = a0;
    dst[1 * HID + tid] = a1;
    dst[2 * HID + tid] = a2;
    dst[3 * HID + tid] = a3;
}

// ---------------------------------------------------------------- k5: MLP scores + softmax + weighted sum (PV split)
__global__ __launch_bounds__(256)
void k5_attn(const float* __restrict__ qp, const float* __restrict__ kcp,
             const float* __restrict__ kmp, const float* __restrict__ vctx,
             const float* __restrict__ Vmem, const float* __restrict__ b1,
             const float* __restrict__ w2, const float* __restrict__ b2,
             float* __restrict__ out, float* __restrict__ outw)
{
    const int bid = blockIdx.x;
    const int t = bid & 127, h = (bid >> 7) & 7, b = bid >> 10;
    const int tid = threadIdx.x;
    const int lane = tid & 63, wv = tid >> 6;
    const int bh = b * H_ + h, bht = bh * TQ_ + t, bt = b * TQ_ + t;
    constexpr int NS = TK_ + TOPK;  // 160
    __shared__ float qps[HID], b1s[HID], w2s[HID];
    __shared__ float sc[NS];
    __shared__ float red[8];
    __shared__ float part[4][DH_];
    if (tid < HID) {
        qps[tid] = qp[(size_t)bht * HID + tid];
        b1s[tid] = b1[tid];
        w2s[tid] = w2[tid];
    }
    __syncthreads();
    const float bias2 = b2[0];
    if (tid < NS) {
        const float* kr = (tid < TK_) ? (kcp + ((size_t)bh * TK_ + tid) * HID)
                                      : (kmp + ((size_t)bt * TOPK + (tid - TK_)) * HID);
        float acc = 0.f;
#pragma unroll 4
        for (int e4 = 0; e4 < HID / 4; ++e4) {
            float4 kv = *reinterpret_cast<const float4*>(kr + e4 * 4);
            acc += fmaxf(qps[e4 * 4 + 0] + kv.x + b1s[e4 * 4 + 0], 0.f) * w2s[e4 * 4 + 0];
            acc += fmaxf(qps[e4 * 4 + 1] + kv.y + b1s[e4 * 4 + 1], 0.f) * w2s[e4 * 4 + 1];
            acc += fmaxf(qps[e4 * 4 + 2] + kv.z + b1s[e4 * 4 + 2], 0.f) * w2s[e4 * 4 + 2];
            acc += fmaxf(qps[e4 * 4 + 3] + kv.w + b1s[e4 * 4 + 3], 0.f) * w2s[e4 * 4 + 3];
        }
        sc[tid] = acc + bias2;
    }
    __syncthreads();
    float v = (tid < NS) ? sc[tid] : -INFINITY;
    float m = v;
#pragma unroll
    for (int off = 1; off < 64; off <<= 1) m = fmaxf(m, __shfl_xor(m, off));
    if (lane == 0) red[wv] = m;
    __syncthreads();
    if (tid == 0) red[4] = fmaxf(fmaxf(red[0], red[1]), fmaxf(red[2], red[3]));
    __syncthreads();
    const float mm = red[4];
    float e = (tid < NS) ? expf(v - mm) : 0.f;
    float ssum = e;
#pragma unroll
    for (int off = 1; off < 64; off <<= 1) ssum += __shfl_xor(ssum, off);
    if (lane == 0) red[wv] = ssum;
    __syncthreads();
    if (tid == 0) red[5] = red[0] + red[1] + red[2] + red[3];
    __syncthreads();
    const float inv = 1.f / red[5];
    if (tid < NS) {
        float w = e * inv;
        sc[tid] = w;
        outw[(size_t)bht * NS + tid] = w;
    }
    __syncthreads();
    // PV: each wave handles 40 s-values for all 64 dims
    {
        const int d = lane;
        const int s0 = wv * 40;
        float acc = 0.f;
        for (int s2 = s0; s2 < s0 + 40; ++s2) {
            const float* vrow = (s2 < TK_)
                ? (vctx + ((size_t)bh * TK_ + s2) * DH_)
                : (Vmem + ((size_t)bt * TOPK + (s2 - TK_)) * DH_);
            acc = fmaf(sc[s2], vrow[d], acc);
        }
        part[wv][d] = acc;
    }
    __syncthreads();
    if (tid < DH_)
        out[(size_t)bht * DH_ + tid] = part[0][tid] + part[1][tid] + part[2][tid] + part[3][tid];
}

// ---------------------------------------------------------------- launch
extern "C" void kernel_launch(void* const* d_in, const int* in_sizes, int n_in,
                              void* d_out, int out_size, void* d_ws, size_t ws_size,
                              hipStream_t stream)
{
    const float* q    = (const float*)d_in[0];
    const float* kctx = (const float*)d_in[1];
    const float* vctx = (const float*)d_in[2];
    const float* qm   = (const float*)d_in[3];
    const float* mk   = (const float*)d_in[4];
    const float* mv   = (const float*)d_in[5];
    const float* Wk   = (const float*)d_in[6];
    const float* Wv   = (const float*)d_in[7];
    const float* W1   = (const float*)d_in[8];
    const float* b1   = (const float*)d_in[9];
    const float* w2   = (const float*)d_in[10];
    const float* b2   = (const float*)d_in[11];
    float* out  = (float*)d_out;
    float* outw = out + (size_t)B_ * H_ * TQ_ * DH_;

    char* w = (char*)d_ws;
    unsigned short* mkb = (unsigned short*)w; w += sizeof(unsigned short) * (size_t)NPAD * DM;
    unsigned short* qmb = (unsigned short*)w; w += sizeof(unsigned short) * R_ * DM;
    unsigned* cand_k = (unsigned*)w; w += sizeof(unsigned) * (size_t)R_ * NCAND;
    int*   cand2_i= (int*)w;   w += sizeof(int) * R_ * CAP;
    int*   cand2_n= (int*)w;   w += sizeof(int) * R_;
    double* rsc   = (double*)w; w += sizeof(double) * R_ * CAP;
    int*   sel    = (int*)w;   w += sizeof(int) * R_ * TOPK;
    float* Vmem   = (float*)w; w += sizeof(float) * R_ * TOPK * DH_;
    float* qp     = (float*)w; w += sizeof(float) * B_ * H_ * TQ_ * HID;
    float* kcp    = (float*)w; w += sizeof(float) * B_ * H_ * TK_ * HID;
    float* kmp    = (float*)w; w += sizeof(float) * R_ * TOPK * HID;

    hipLaunchKernelGGL(k0_cvt, dim3(4096), dim3(256), 0, stream, mk, qm, mkb);
    hipLaunchKernelGGL(k1_mfma, dim3(NCHP * 4), dim3(256), 0, stream, qmb, mkb, cand_k);
    hipLaunchKernelGGL(k2a_thresh, dim3(R_), dim3(256), 0, stream, cand_k, cand2_i, cand2_n);
    hipLaunchKernelGGL(k2b_rescore, dim3(R_, CAP / 4), dim3(256), 0, stream, qm, mk, cand2_i, cand2_n, rsc);
    hipLaunchKernelGGL(k2c_top32, dim3(R_), dim3(64), 0, stream, rsc, cand2_i, cand2_n, sel);
    hipLaunchKernelGGL(k3_proj, dim3(R_ * TOPK / 8), dim3(128), 0, stream, mk, mv, Wk, Wv, W1, sel, kmp, Vmem);
    hipLaunchKernelGGL(k4_parts, dim3(2048), dim3(128), 0, stream, q, kctx, W1, qp, kcp);
    hipLaunchKernelGGL(k5_attn, dim3(B_ * H_ * TQ_), dim3(256), 0, stream, qp, kcp, kmp, vctx, Vmem, b1, w2, b2, out, outw);
}

// Round 11
// 361.561 us; speedup vs baseline: 1.0626x; 1.0010x over previous
//
#include <hip/hip_runtime.h>
#include <cmath>

constexpr int B_ = 4, H_ = 8, TQ_ = 128, TK_ = 128, DH_ = 64;
constexpr int NMEM = 100000, DM = 512, TOPK = 32, HID = 128;
constexpr int R_ = B_ * TQ_;                    // 512 memory rows (b,t)
constexpr int CTILE = 128, RTILE = 128;         // 128x128 output tile
constexpr int NCHP = 784;                       // padded chunk count (8 XCDs x 98)
constexpr int NPAD = NCHP * CTILE;              // 100352 padded rows
constexpr int KC = 16;                          // candidates kept per chunk
constexpr int NCAND = NCHP * KC;                // 12544 = 49*256
constexpr int KSEL = 48;                        // min rescored candidates
constexpr int CAP  = 128;                       // max rescored candidates
constexpr int NLD  = NCAND / 256;               // 49 keys per thread (exact)

using f32x4  = __attribute__((ext_vector_type(4))) float;
using bf16x8 = __attribute__((ext_vector_type(8))) short;
using u16x8  = __attribute__((ext_vector_type(8))) unsigned short;

#define GLOAD16(g, l) __builtin_amdgcn_global_load_lds( \
    (const __attribute__((address_space(1))) void*)(g), \
    (__attribute__((address_space(3))) void*)(l), 16, 0, 0)

static __device__ __forceinline__ unsigned short f2bf(float f) {
    unsigned u = __float_as_uint(f);
    u = (u + 0x7FFFu + ((u >> 16) & 1u)) >> 16;
    return (unsigned short)u;
}

// ---------------------------------------------------------------- k0: fp32 -> bf16 (mk padded + qm, one kernel)
__global__ __launch_bounds__(256)
void k0_cvt(const float* __restrict__ mk, const float* __restrict__ qm,
            unsigned short* __restrict__ dst)
{
    const long totalmk = (long)NPAD * DM;          // bf16 elements for mk region
    const long nvalid  = (long)NMEM * DM;
    const long total   = totalmk + (long)R_ * DM;
    long stride = (long)gridDim.x * 256 * 8;
    for (long base = ((long)blockIdx.x * 256 + threadIdx.x) * 8; base < total; base += stride) {
        u16x8 o;
        const float* src = nullptr;
        long off = 0;
        if (base < totalmk) {
            if (base < nvalid) { src = mk; off = base; }
        } else { src = qm; off = base - totalmk; }
        if (src) {
            float4 v0 = *reinterpret_cast<const float4*>(src + off);
            float4 v1 = *reinterpret_cast<const float4*>(src + off + 4);
            o[0] = f2bf(v0.x); o[1] = f2bf(v0.y); o[2] = f2bf(v0.z); o[3] = f2bf(v0.w);
            o[4] = f2bf(v1.x); o[5] = f2bf(v1.y); o[6] = f2bf(v1.z); o[7] = f2bf(v1.w);
        } else {
            o = (u16x8)0;
        }
        *reinterpret_cast<u16x8*>(dst + base) = o;
    }
}

// ---------------------------------------------------------------- kT: weight transposes (d-major, float4-blocked)
// WT4  : [DM/4][128][4]  e<64 -> Wk row e, e>=64 -> Wv row e-64
// W1qT4: [DH/4][128][4]  W1[e][0:64]
// W1kT4: [DH/4][128][4]  W1[e][64:128]
__global__ __launch_bounds__(256)
void kT_transpose(const float* __restrict__ Wk, const float* __restrict__ Wv,
                  const float* __restrict__ W1, float* __restrict__ WT4,
                  float* __restrict__ W1qT4, float* __restrict__ W1kT4)
{
    int i = blockIdx.x * 256 + threadIdx.x;
    if (i < 512 * 128) {
        int e = (i >> 2) & 127;
        int d = (i >> 9) * 4 + (i & 3);
        WT4[i] = (e < 64) ? Wk[(size_t)e * DM + d] : Wv[(size_t)(e - 64) * DM + d];
    } else if (i < 512 * 128 + 64 * 128) {
        int j = i - 512 * 128;
        int e = (j >> 2) & 127;
        int d = (j >> 9) * 4 + (j & 3);
        W1qT4[j] = W1[(size_t)e * (2 * DH_) + d];
        W1kT4[j] = W1[(size_t)e * (2 * DH_) + DH_ + d];
    }
}

// ---------------------------------------------------------------- k1: bf16 MFMA 128x128 tile + per-chunk top-16
__global__ __launch_bounds__(256)
void k1_mfma(const unsigned short* __restrict__ qmb, const unsigned short* __restrict__ mkb,
             unsigned* __restrict__ cand_k)
{
    const int wgid = blockIdx.x;          // 0..3135
    const int xcd = wgid & 7;
    const int k9 = wgid >> 3;             // 0..391
    const int chunk = xcd * 98 + (k9 >> 2);
    const int rt = k9 & 3;
    const int row0 = rt * RTILE;
    const int col0 = chunk * CTILE;
    const int tid = threadIdx.x;
    const int lane = tid & 63, w = tid >> 6;
    const int wm = w >> 1, wn = w & 1;    // wave computes 64x64

    __shared__ __align__(16) char smem[64 * 132 * 4];
    char* Abase = smem;
    char* Bbase = smem + 16384;
    float* scf = (float*)smem;

    const char* srcA[4];
    const char* srcB[4];
#pragma unroll
    for (int p = 0; p < 4; ++p) {
        int X = p * 4096 + w * 1024 + lane * 16;
        int r = X >> 7, c = (X & 127) ^ ((r & 7) << 4);
        srcA[p] = (const char*)qmb + (size_t)(row0 + r) * 1024 + c;
        srcB[p] = (const char*)mkb + (size_t)(col0 + r) * 1024 + c;
    }
    int aoff[4][2], boff[4][2];
#pragma unroll
    for (int mi = 0; mi < 4; ++mi) {
        int rr = wm * 64 + mi * 16 + (lane & 15);
        int bse = rr * 128 + ((lane >> 4) * 16);
        aoff[mi][0] = bse ^ ((rr & 7) << 4);
        aoff[mi][1] = (bse + 64) ^ ((rr & 7) << 4);
    }
#pragma unroll
    for (int ni = 0; ni < 4; ++ni) {
        int rr = wn * 64 + ni * 16 + (lane & 15);
        int bse = rr * 128 + ((lane >> 4) * 16);
        boff[ni][0] = 16384 + (bse ^ ((rr & 7) << 4));
        boff[ni][1] = 16384 + ((bse + 64) ^ ((rr & 7) << 4));
    }

    f32x4 acc[4][4];
#pragma unroll
    for (int mi = 0; mi < 4; ++mi)
#pragma unroll
        for (int ni = 0; ni < 4; ++ni) acc[mi][ni] = (f32x4)0.f;

    for (int ks = 0; ks < 8; ++ks) {
#pragma unroll
        for (int p = 0; p < 4; ++p) {
            GLOAD16(srcA[p], Abase + p * 4096 + w * 1024);
            srcA[p] += 128;
            GLOAD16(srcB[p], Bbase + p * 4096 + w * 1024);
            srcB[p] += 128;
        }
        __syncthreads();
#pragma unroll
        for (int kk = 0; kk < 2; ++kk) {
            bf16x8 af[4], bfr[4];
#pragma unroll
            for (int mi = 0; mi < 4; ++mi)
                af[mi] = *reinterpret_cast<const bf16x8*>(smem + aoff[mi][kk]);
#pragma unroll
            for (int ni = 0; ni < 4; ++ni)
                bfr[ni] = *reinterpret_cast<const bf16x8*>(smem + boff[ni][kk]);
#pragma unroll
            for (int mi = 0; mi < 4; ++mi)
#pragma unroll
                for (int ni = 0; ni < 4; ++ni)
                    acc[mi][ni] = __builtin_amdgcn_mfma_f32_16x16x32_bf16(af[mi], bfr[ni], acc[mi][ni], 0, 0, 0);
        }
        __syncthreads();
    }

    // selection in two row-halves; scores PERMUTED: pos = (cc&31)*4 + (cc>>5)
    const int rid = tid >> 2, sub = tid & 3;
    const int bsub = 127 - sub * 8;
#pragma unroll
    for (int h = 0; h < 2; ++h) {
        if (wm == h) {
#pragma unroll
            for (int mi = 0; mi < 4; ++mi)
#pragma unroll
                for (int ni = 0; ni < 4; ++ni)
#pragma unroll
                    for (int reg = 0; reg < 4; ++reg) {
                        int rr = mi * 16 + (lane >> 4) * 4 + reg;      // 0..63 local
                        int cc = wn * 64 + ni * 16 + (lane & 15);
                        int pos = ((cc & 31) << 2) | (cc >> 5);
                        scf[rr * 132 + pos] = (col0 + cc < NMEM) ? acc[mi][ni][reg] : -INFINITY;
                    }
        }
        __syncthreads();

        const float* srow = scf + rid * 132 + sub * 32;
        unsigned t0 = 0u, t1 = 0u, t2 = 0u, t3 = 0u;
#pragma unroll
        for (int i = 0; i < 8; ++i) {
            float4 v4 = *reinterpret_cast<const float4*>(srow + i * 4);
            float vv[4] = {v4.x, v4.y, v4.z, v4.w};
#pragma unroll
            for (int q = 0; q < 4; ++q) {
                unsigned b = __float_as_uint(vv[q]);
                unsigned s = b ^ ((unsigned)((int)b >> 31) | 0x80000000u);   // order-preserving
                unsigned key = (s & 0xFFFFFF80u) | (unsigned)(bsub - (q * 32 + i));
                bool g0 = key > t0, g1 = key > t1, g2 = key > t2, g3 = key > t3;
                unsigned n0 = g0 ? key : t0;
                unsigned n1 = g0 ? t0 : (g1 ? key : t1);
                unsigned n2 = g1 ? t1 : (g2 ? key : t2);
                unsigned n3 = g2 ? t2 : (g3 ? key : t3);
                t0 = n0; t1 = n1; t2 = n2; t3 = n3;
            }
        }
        size_t base = (size_t)(row0 + h * 64 + rid) * NCAND + (size_t)chunk * KC + sub * 4;
        *reinterpret_cast<uint4*>(cand_k + base) = make_uint4(t0, t1, t2, t3);
        __syncthreads();
    }
}

// ---------------------------------------------------------------- k2a: threshold select + gather (indices derived from keys)
__global__ __launch_bounds__(256)
void k2a_thresh(const unsigned* __restrict__ cand_k,
                int* __restrict__ cand2_i, int* __restrict__ cand2_n)
{
    const int row = blockIdx.x;
    const int tid = threadIdx.x;
    const int lane = tid & 63, wv = tid >> 6;
    const unsigned* ck = cand_k + (size_t)row * NCAND;

    unsigned key[NLD];
#pragma unroll
    for (int j = 0; j < NLD; ++j) key[j] = ck[tid + j * 256];

    __shared__ int red[4];
    __shared__ int cnt;
    unsigned lo = 0u;
    int c_cur = NCAND;
    for (int bit = 31; bit >= 0; --bit) {
        if (c_cur <= CAP) break;   // uniform across block
        unsigned T = lo | (1u << bit);
        int c = 0;
#pragma unroll
        for (int j = 0; j < NLD; ++j) c += (key[j] >= T);
#pragma unroll
        for (int off = 1; off < 64; off <<= 1) c += __shfl_xor(c, off);
        if (lane == 0) red[wv] = c;
        __syncthreads();
        int ct = red[0] + red[1] + red[2] + red[3];
        if (ct >= KSEL) { lo = T; c_cur = ct; }
        __syncthreads();
    }

    if (tid == 0) cnt = 0;
    __syncthreads();
#pragma unroll
    for (int j = 0; j < NLD; ++j) {
        if (key[j] >= lo) {
            int p = atomicAdd(&cnt, 1);
            if (p < CAP) {
                int ipos = tid + j * 256;
                int chunk = ipos >> 4;                      // /KC
                int col = (chunk << 7) + 127 - (int)(key[j] & 127u);
                cand2_i[(size_t)row * CAP + p] = col;
            }
        }
    }
    __syncthreads();
    if (tid == 0) cand2_n[row] = cnt < CAP ? cnt : CAP;
}

// ---------------------------------------------------------------- k2b: fp64 rescore (one wave per candidate, float4 loads)
__global__ __launch_bounds__(256)
void k2b_rescore(const float* __restrict__ qm, const float* __restrict__ mk,
                 const int* __restrict__ cand2_i, const int* __restrict__ cand2_n,
                 double* __restrict__ rsc)
{
    const int row = blockIdx.x;
    const int tid = threadIdx.x;
    const int lane = tid & 63, wv = tid >> 6;
    const int c = blockIdx.y * 4 + wv;
    const int n = cand2_n[row];
    if (c >= n) return;
    const int idx = cand2_i[(size_t)row * CAP + c];
    const float4* q4 = reinterpret_cast<const float4*>(qm + (size_t)row * DM);
    const float4* k4 = reinterpret_cast<const float4*>(mk + (size_t)idx * DM);
    float4 a0 = q4[lane], b0 = k4[lane];
    float4 a1 = q4[lane + 64], b1 = k4[lane + 64];
    double p = (double)a0.x * b0.x + (double)a0.y * b0.y
             + (double)a0.z * b0.z + (double)a0.w * b0.w
             + (double)a1.x * b1.x + (double)a1.y * b1.y
             + (double)a1.z * b1.z + (double)a1.w * b1.w;
#pragma unroll
    for (int off = 1; off < 64; off <<= 1) p += __shfl_xor(p, off);
    if (lane == 0) rsc[(size_t)row * CAP + c] = p;
}

// ---------------------------------------------------------------- k2c: exact ordered top-32 (one wave per row)
__global__ __launch_bounds__(64)
void k2c_top32(const double* __restrict__ rsc, const int* __restrict__ cand2_i,
               const int* __restrict__ cand2_n, int* __restrict__ sel)
{
    const int row = blockIdx.x;
    const int lane = threadIdx.x;
    const int n = cand2_n[row];
    double v0 = -1.0e300, v1 = -1.0e300;
    int i0 = 0x7fffffff, i1 = 0x7fffffff;
    if (lane < n)      { v0 = rsc[(size_t)row * CAP + lane];      i0 = cand2_i[(size_t)row * CAP + lane]; }
    if (lane + 64 < n) { v1 = rsc[(size_t)row * CAP + lane + 64]; i1 = cand2_i[(size_t)row * CAP + lane + 64]; }
    for (int s = 0; s < TOPK; ++s) {
        double bv; int bi;
        if (v0 > v1 || (v0 == v1 && i0 < i1)) { bv = v0; bi = i0; }
        else                                  { bv = v1; bi = i1; }
#pragma unroll
        for (int off = 1; off < 64; off <<= 1) {
            double ov = __shfl_xor(bv, off);
            int    oi = __shfl_xor(bi, off);
            if (ov > bv || (ov == bv && oi < bi)) { bv = ov; bi = oi; }
        }
        if (lane == 0) sel[row * TOPK + s] = bi;
        if (i0 == bi) v0 = -1.0e300;
        if (i1 == bi) v1 = -1.0e300;
    }
}

// ---------------------------------------------------------------- k3: gather + projection (coalesced WT4) + fused kmp
__global__ __launch_bounds__(128)
void k3_proj(const float* __restrict__ mk, const float* __restrict__ mv,
             const float4* __restrict__ WT4, const float4* __restrict__ W1kT4,
             const int* __restrict__ sel,
             float* __restrict__ kmp, float* __restrict__ Vmem)
{
    const int i0 = blockIdx.x * 8;   // pair base, pair = row*TOPK+k (16384 total)
    const int tid = threadIdx.x;     // 128
    __shared__ float s[2][8][DM];    // [mat][row][d] 32 KiB
    __shared__ float sKm[8][DH_];    // projected K rows, 2 KiB
    __shared__ int si[8];
    if (tid < 8) si[tid] = sel[i0 + tid];
    __syncthreads();
    for (int l = tid; l < 2048; l += 128) {   // 2 mats x 8 rows x 128 float4
        int mat = l >> 10, r = (l >> 7) & 7, c4 = l & 127;
        const float* src = (mat ? mv : mk) + (size_t)si[r] * DM + c4 * 4;
        *reinterpret_cast<float4*>(&s[mat][r][c4 * 4]) =
            *reinterpret_cast<const float4*>(src);
    }
    __syncthreads();
    const int doV = tid >> 6;        // 0: K path (e=tid), 1: V path (e=tid-64)
    float a0[8];
#pragma unroll
    for (int r = 0; r < 8; ++r) a0[r] = 0.f;
    for (int d4 = 0; d4 < DM / 4; ++d4) {
        float4 x0 = WT4[d4 * 128 + tid];     // coalesced: wave reads 1KB contiguous
#pragma unroll
        for (int r = 0; r < 8; ++r) {
            float4 m = *reinterpret_cast<const float4*>(&s[doV][r][d4 * 4]);
            a0[r] = fmaf(x0.x, m.x, fmaf(x0.y, m.y, fmaf(x0.z, m.z, fmaf(x0.w, m.w, a0[r]))));
        }
    }
    if (doV) {
        const int ep = tid & 63;
#pragma unroll
        for (int r = 0; r < 8; ++r)
            Vmem[(size_t)(i0 + r) * DH_ + ep] = a0[r];
    } else {
#pragma unroll
        for (int r = 0; r < 8; ++r)
            sKm[r][tid] = a0[r];
    }
    __syncthreads();
    // kmp[e] for the 8 rows: e = tid (0..127), coalesced W1kT4 reads
    float acc[8];
#pragma unroll
    for (int r = 0; r < 8; ++r) acc[r] = 0.f;
    for (int d4 = 0; d4 < DH_ / 4; ++d4) {
        float4 xw = W1kT4[d4 * 128 + tid];
#pragma unroll
        for (int r = 0; r < 8; ++r) {
            float4 m = *reinterpret_cast<const float4*>(&sKm[r][d4 * 4]);
            acc[r] = fmaf(xw.x, m.x, fmaf(xw.y, m.y, fmaf(xw.z, m.z, fmaf(xw.w, m.w, acc[r]))));
        }
    }
#pragma unroll
    for (int r = 0; r < 8; ++r)
        kmp[(size_t)(i0 + r) * HID + tid] = acc[r];
}

// ---------------------------------------------------------------- k4: W1 partial projections (q, kctx; coalesced W1T4)
__global__ __launch_bounds__(128)
void k4_parts(const float* __restrict__ q, const float* __restrict__ kctx,
              const float4* __restrict__ W1qT4, const float4* __restrict__ W1kT4,
              float* __restrict__ qp, float* __restrict__ kcp)
{
    const int bid = blockIdx.x;
    const int tid = threadIdx.x;  // 128 = e
    const float* src; float* dst; const float4* WT;
    if (bid < 1024)      { int r0 = bid * 4;          src = q    + (size_t)r0 * DH_; dst = qp  + (size_t)r0 * HID; WT = W1qT4; }
    else                 { int r0 = (bid - 1024) * 4; src = kctx + (size_t)r0 * DH_; dst = kcp + (size_t)r0 * HID; WT = W1kT4; }
    __shared__ float s[4][DH_];
    for (int l = tid; l < 4 * DH_; l += 128) s[l >> 6][l & 63] = src[l];
    __syncthreads();
    float a[4];
#pragma unroll
    for (int r = 0; r < 4; ++r) a[r] = 0.f;
    for (int d4 = 0; d4 < DH_ / 4; ++d4) {
        float4 x = WT[d4 * 128 + tid];
#pragma unroll
        for (int r = 0; r < 4; ++r) {
            float4 m = *reinterpret_cast<const float4*>(&s[r][d4 * 4]);
            a[r] = fmaf(x.x, m.x, fmaf(x.y, m.y, fmaf(x.z, m.z, fmaf(x.w, m.w, a[r]))));
        }
    }
#pragma unroll
    for (int r = 0; r < 4; ++r)
        dst[(size_t)r * HID + tid] = a[r];
}

// ---------------------------------------------------------------- k5: MLP scores + softmax + weighted sum (PV split)
__global__ __launch_bounds__(256)
void k5_attn(const float* __restrict__ qp, const float* __restrict__ kcp,
             const float* __restrict__ kmp, const float* __restrict__ vctx,
             const float* __restrict__ Vmem, const float* __restrict__ b1,
             const float* __restrict__ w2, const float* __restrict__ b2,
             float* __restrict__ out, float* __restrict__ outw)
{
    const int bid = blockIdx.x;
    const int t = bid & 127, h = (bid >> 7) & 7, b = bid >> 10;
    const int tid = threadIdx.x;
    const int lane = tid & 63, wv = tid >> 6;
    const int bh = b * H_ + h, bht = bh * TQ_ + t, bt = b * TQ_ + t;
    constexpr int NS = TK_ + TOPK;  // 160
    __shared__ float qps[HID], b1s[HID], w2s[HID];
    __shared__ float sc[NS];
    __shared__ float red[8];
    __shared__ float part[4][DH_];
    if (tid < HID) {
        qps[tid] = qp[(size_t)bht * HID + tid];
        b1s[tid] = b1[tid];
        w2s[tid] = w2[tid];
    }
    __syncthreads();
    const float bias2 = b2[0];
    if (tid < NS) {
        const float* kr = (tid < TK_) ? (kcp + ((size_t)bh * TK_ + tid) * HID)
                                      : (kmp + ((size_t)bt * TOPK + (tid - TK_)) * HID);
        float acc = 0.f;
#pragma unroll 4
        for (int e4 = 0; e4 < HID / 4; ++e4) {
            float4 kv = *reinterpret_cast<const float4*>(kr + e4 * 4);
            acc += fmaxf(qps[e4 * 4 + 0] + kv.x + b1s[e4 * 4 + 0], 0.f) * w2s[e4 * 4 + 0];
            acc += fmaxf(qps[e4 * 4 + 1] + kv.y + b1s[e4 * 4 + 1], 0.f) * w2s[e4 * 4 + 1];
            acc += fmaxf(qps[e4 * 4 + 2] + kv.z + b1s[e4 * 4 + 2], 0.f) * w2s[e4 * 4 + 2];
            acc += fmaxf(qps[e4 * 4 + 3] + kv.w + b1s[e4 * 4 + 3], 0.f) * w2s[e4 * 4 + 3];
        }
        sc[tid] = acc + bias2;
    }
    __syncthreads();
    float v = (tid < NS) ? sc[tid] : -INFINITY;
    float m = v;
#pragma unroll
    for (int off = 1; off < 64; off <<= 1) m = fmaxf(m, __shfl_xor(m, off));
    if (lane == 0) red[wv] = m;
    __syncthreads();
    if (tid == 0) red[4] = fmaxf(fmaxf(red[0], red[1]), fmaxf(red[2], red[3]));
    __syncthreads();
    const float mm = red[4];
    float e = (tid < NS) ? expf(v - mm) : 0.f;
    float ssum = e;
#pragma unroll
    for (int off = 1; off < 64; off <<= 1) ssum += __shfl_xor(ssum, off);
    if (lane == 0) red[wv] = ssum;
    __syncthreads();
    if (tid == 0) red[5] = red[0] + red[1] + red[2] + red[3];
    __syncthreads();
    const float inv = 1.f / red[5];
    if (tid < NS) {
        float w = e * inv;
        sc[tid] = w;
        outw[(size_t)bht * NS + tid] = w;
    }
    __syncthreads();
    // PV: each wave handles 40 s-values for all 64 dims
    {
        const int d = lane;
        const int s0 = wv * 40;
        float acc = 0.f;
        for (int s2 = s0; s2 < s0 + 40; ++s2) {
            const float* vrow = (s2 < TK_)
                ? (vctx + ((size_t)bh * TK_ + s2) * DH_)
                : (Vmem + ((size_t)bt * TOPK + (s2 - TK_)) * DH_);
            acc = fmaf(sc[s2], vrow[d], acc);
        }
        part[wv][d] = acc;
    }
    __syncthreads();
    if (tid < DH_)
        out[(size_t)bht * DH_ + tid] = part[0][tid] + part[1][tid] + part[2][tid] + part[3][tid];
}

// ---------------------------------------------------------------- launch
extern "C" void kernel_launch(void* const* d_in, const int* in_sizes, int n_in,
                              void* d_out, int out_size, void* d_ws, size_t ws_size,
                              hipStream_t stream)
{
    const float* q    = (const float*)d_in[0];
    const float* kctx = (const float*)d_in[1];
    const float* vctx = (const float*)d_in[2];
    const float* qm   = (const float*)d_in[3];
    const float* mk   = (const float*)d_in[4];
    const float* mv   = (const float*)d_in[5];
    const float* Wk   = (const float*)d_in[6];
    const float* Wv   = (const float*)d_in[7];
    const float* W1   = (const float*)d_in[8];
    const float* b1   = (const float*)d_in[9];
    const float* w2   = (const float*)d_in[10];
    const float* b2   = (const float*)d_in[11];
    float* out  = (float*)d_out;
    float* outw = out + (size_t)B_ * H_ * TQ_ * DH_;

    char* w = (char*)d_ws;
    unsigned short* mkb = (unsigned short*)w; w += sizeof(unsigned short) * (size_t)NPAD * DM;
    unsigned short* qmb = (unsigned short*)w; w += sizeof(unsigned short) * R_ * DM;
    float* WT4   = (float*)w;  w += sizeof(float) * 512 * 128;
    float* W1qT4 = (float*)w;  w += sizeof(float) * 64 * 128;
    float* W1kT4 = (float*)w;  w += sizeof(float) * 64 * 128;
    unsigned* cand_k = (unsigned*)w; w += sizeof(unsigned) * (size_t)R_ * NCAND;
    int*   cand2_i= (int*)w;   w += sizeof(int) * R_ * CAP;
    int*   cand2_n= (int*)w;   w += sizeof(int) * R_;
    double* rsc   = (double*)w; w += sizeof(double) * R_ * CAP;
    int*   sel    = (int*)w;   w += sizeof(int) * R_ * TOPK;
    float* Vmem   = (float*)w; w += sizeof(float) * R_ * TOPK * DH_;
    float* qp     = (float*)w; w += sizeof(float) * B_ * H_ * TQ_ * HID;
    float* kcp    = (float*)w; w += sizeof(float) * B_ * H_ * TK_ * HID;
    float* kmp    = (float*)w; w += sizeof(float) * R_ * TOPK * HID;

    hipLaunchKernelGGL(kT_transpose, dim3(288), dim3(256), 0, stream, Wk, Wv, W1, WT4, W1qT4, W1kT4);
    hipLaunchKernelGGL(k0_cvt, dim3(4096), dim3(256), 0, stream, mk, qm, mkb);
    hipLaunchKernelGGL(k1_mfma, dim3(NCHP * 4), dim3(256), 0, stream, qmb, mkb, cand_k);
    hipLaunchKernelGGL(k2a_thresh, dim3(R_), dim3(256), 0, stream, cand_k, cand2_i, cand2_n);
    hipLaunchKernelGGL(k2b_rescore, dim3(R_, CAP / 4), dim3(256), 0, stream, qm, mk, cand2_i, cand2_n, rsc);
    hipLaunchKernelGGL(k2c_top32, dim3(R_), dim3(64), 0, stream, rsc, cand2_i, cand2_n, sel);
    hipLaunchKernelGGL(k3_proj, dim3(R_ * TOPK / 8), dim3(128), 0, stream, mk, mv,
                       (const float4*)WT4, (const float4*)W1kT4, sel, kmp, Vmem);
    hipLaunchKernelGGL(k4_parts, dim3(2048), dim3(128), 0, stream, q, kctx,
                       (const float4*)W1qT4, (const float4*)W1kT4, qp, kcp);
    hipLaunchKernelGGL(k5_attn, dim3(B_ * H_ * TQ_), dim3(256), 0, stream, qp, kcp, kmp, vctx, Vmem, b1, w2, b2, out, outw);
}